// Round 12
// baseline (196.439 us; speedup 1.0000x reference)
//
#include <hip/hip_runtime.h>

typedef unsigned short ushort_t;
typedef __attribute__((ext_vector_type(8))) short bh8;     // 8 bf16 (4 VGPRs)
typedef __attribute__((ext_vector_type(4))) float f4;      // 4 fp32 acc
typedef __attribute__((ext_vector_type(4))) unsigned int u4;

__device__ __forceinline__ ushort_t f2bf(float f) {
  unsigned u = __float_as_uint(f);
  return (ushort_t)((u + 0x7FFFu + ((u >> 16) & 1u)) >> 16);
}
__device__ __forceinline__ float bf2f(ushort_t v) {
  return __uint_as_float(((unsigned)v) << 16);
}

// ---------------------------------------------------------------------------
// bf16 MFMA GEMM core, abt form, LDS passed in (20480 B: As 10240 + Bs 10240)
// Register double-buffered staging (R1).
// ---------------------------------------------------------------------------
template <typename OutT>
__device__ __forceinline__ void gemm_abt_core(
    char* smem,
    const ushort_t* __restrict__ A, const ushort_t* __restrict__ B,
    OutT* __restrict__ C, int ldA, int ldB, int ldC, int K, int m0, int n0)
{
  ushort_t* As = (ushort_t*)smem;
  ushort_t* Bs = (ushort_t*)(smem + 10240);
  int t = threadIdx.x;
  int lane = t & 63, w = t >> 6;
  int quad = lane >> 4, l15 = lane & 15;
  int wm = w >> 1, wn = w & 1;
  f4 acc[4][4];
  #pragma unroll
  for (int mi = 0; mi < 4; ++mi)
    #pragma unroll
    for (int ni = 0; ni < 4; ++ni) acc[mi][ni] = (f4)0.f;
  int row = t >> 1, kh = (t & 1) * 16;
  const ushort_t* pa = A + (m0 + row) * ldA + kh;
  const ushort_t* pb = B + (n0 + row) * ldB + kh;
  u4 va0 = *(const u4*)(pa);     u4 va1 = *(const u4*)(pa + 8);
  u4 vb0 = *(const u4*)(pb);     u4 vb1 = *(const u4*)(pb + 8);
  for (int k0 = 0; k0 < K; k0 += 32) {
    if (k0) __syncthreads();
    {
      u4* da = (u4*)(As + row * 40 + kh); da[0] = va0; da[1] = va1;
      u4* db = (u4*)(Bs + row * 40 + kh); db[0] = vb0; db[1] = vb1;
    }
    if (k0 + 32 < K) {
      va0 = *(const u4*)(pa + k0 + 32); va1 = *(const u4*)(pa + k0 + 40);
      vb0 = *(const u4*)(pb + k0 + 32); vb1 = *(const u4*)(pb + k0 + 40);
    }
    __syncthreads();
    bh8 af[4], bfv[4];
    #pragma unroll
    for (int mi = 0; mi < 4; ++mi)
      af[mi] = *(bh8*)(As + (wm * 64 + mi * 16 + l15) * 40 + quad * 8);
    #pragma unroll
    for (int ni = 0; ni < 4; ++ni)
      bfv[ni] = *(bh8*)(Bs + (wn * 64 + ni * 16 + l15) * 40 + quad * 8);
    #pragma unroll
    for (int mi = 0; mi < 4; ++mi)
      #pragma unroll
      for (int ni = 0; ni < 4; ++ni)
        acc[mi][ni] = __builtin_amdgcn_mfma_f32_16x16x32_bf16(af[mi], bfv[ni], acc[mi][ni], 0, 0, 0);
  }
  #pragma unroll
  for (int mi = 0; mi < 4; ++mi)
    #pragma unroll
    for (int ni = 0; ni < 4; ++ni)
      #pragma unroll
      for (int r = 0; r < 4; ++r) {
        int mg = m0 + wm * 64 + mi * 16 + quad * 4 + r;
        int ng = n0 + wn * 64 + ni * 16 + l15;
        if constexpr (sizeof(OutT) == 4) C[mg * ldC + ng] = acc[mi][ni][r];
        else C[mg * ldC + ng] = (OutT)f2bf(acc[mi][ni][r]);
      }
}

// ---------------------------------------------------------------------------
// 128x64-tile variant (R5; R9: also used by gemm_val_k for 2x blocks).
// ---------------------------------------------------------------------------
__device__ __forceinline__ void gemm_abt_12864(
    char* smem,
    const ushort_t* __restrict__ A, const ushort_t* __restrict__ B,
    float* __restrict__ C, int ldA, int ldB, int ldC, int K, int m0, int n0)
{
  ushort_t* As = (ushort_t*)smem;
  ushort_t* Bs = (ushort_t*)(smem + 10240);
  int t = threadIdx.x;
  int lane = t & 63, w = t >> 6;
  int quad = lane >> 4, l15 = lane & 15;
  int wm = w >> 1, wn = w & 1;
  f4 acc[4][2];
  #pragma unroll
  for (int mi = 0; mi < 4; ++mi)
    #pragma unroll
    for (int ni = 0; ni < 2; ++ni) acc[mi][ni] = (f4)0.f;
  int rowA = t >> 1, khA = (t & 1) * 16;
  int rowB = t >> 2, khB = (t & 3) * 8;
  const ushort_t* pa = A + (m0 + rowA) * ldA + khA;
  const ushort_t* pb = B + (n0 + rowB) * ldB + khB;
  u4 va0 = *(const u4*)(pa); u4 va1 = *(const u4*)(pa + 8);
  u4 vb0 = *(const u4*)(pb);
  for (int k0 = 0; k0 < K; k0 += 32) {
    if (k0) __syncthreads();
    {
      u4* da = (u4*)(As + rowA * 40 + khA); da[0] = va0; da[1] = va1;
      u4* db = (u4*)(Bs + rowB * 40 + khB); db[0] = vb0;
    }
    if (k0 + 32 < K) {
      va0 = *(const u4*)(pa + k0 + 32); va1 = *(const u4*)(pa + k0 + 40);
      vb0 = *(const u4*)(pb + k0 + 32);
    }
    __syncthreads();
    bh8 af[4], bf2[2];
    #pragma unroll
    for (int mi = 0; mi < 4; ++mi)
      af[mi] = *(bh8*)(As + (wm * 64 + mi * 16 + l15) * 40 + quad * 8);
    #pragma unroll
    for (int ni = 0; ni < 2; ++ni)
      bf2[ni] = *(bh8*)(Bs + (wn * 32 + ni * 16 + l15) * 40 + quad * 8);
    #pragma unroll
    for (int mi = 0; mi < 4; ++mi)
      #pragma unroll
      for (int ni = 0; ni < 2; ++ni)
        acc[mi][ni] = __builtin_amdgcn_mfma_f32_16x16x32_bf16(af[mi], bf2[ni], acc[mi][ni], 0, 0, 0);
  }
  #pragma unroll
  for (int mi = 0; mi < 4; ++mi)
    #pragma unroll
    for (int ni = 0; ni < 2; ++ni)
      #pragma unroll
      for (int r = 0; r < 4; ++r) {
        int mg = m0 + wm * 64 + mi * 16 + quad * 4 + r;
        int ng = n0 + wn * 32 + ni * 16 + l15;
        C[mg * ldC + ng] = acc[mi][ni][r];
      }
}

// ---------------------------------------------------------------------------
// fp32-input variant (R7 form: no register prefetch).
// ---------------------------------------------------------------------------
__device__ __forceinline__ void gemm_abt_f32in(
    char* smem,
    const float* __restrict__ A, const float* __restrict__ B,
    ushort_t* __restrict__ C, int ldA, int ldB, int ldC, int K, int m0, int n0)
{
  ushort_t* As = (ushort_t*)smem;
  ushort_t* Bs = (ushort_t*)(smem + 10240);
  int t = threadIdx.x;
  int lane = t & 63, w = t >> 6;
  int quad = lane >> 4, l15 = lane & 15;
  int wm = w >> 1, wn = w & 1;
  f4 acc[4][4];
  #pragma unroll
  for (int mi = 0; mi < 4; ++mi)
    #pragma unroll
    for (int ni = 0; ni < 4; ++ni) acc[mi][ni] = (f4)0.f;
  int row = t >> 1, kh = (t & 1) * 16;
  const float* pa = A + (m0 + row) * ldA + kh;
  const float* pb = B + (n0 + row) * ldB + kh;
  for (int k0 = 0; k0 < K; k0 += 32) {
    if (k0) __syncthreads();
    {
      ushort_t* da = As + row * 40 + kh;
      ushort_t* db = Bs + row * 40 + kh;
      #pragma unroll
      for (int i = 0; i < 4; ++i) {
        float4 fa = *(const float4*)(pa + k0 + i * 4);
        float4 fb = *(const float4*)(pb + k0 + i * 4);
        ushort4 oa; oa.x = f2bf(fa.x); oa.y = f2bf(fa.y);
        oa.z = f2bf(fa.z); oa.w = f2bf(fa.w);
        *(ushort4*)(da + i * 4) = oa;
        ushort4 ob; ob.x = f2bf(fb.x); ob.y = f2bf(fb.y);
        ob.z = f2bf(fb.z); ob.w = f2bf(fb.w);
        *(ushort4*)(db + i * 4) = ob;
      }
    }
    __syncthreads();
    bh8 af[4], bfv[4];
    #pragma unroll
    for (int mi = 0; mi < 4; ++mi)
      af[mi] = *(bh8*)(As + (wm * 64 + mi * 16 + l15) * 40 + quad * 8);
    #pragma unroll
    for (int ni = 0; ni < 4; ++ni)
      bfv[ni] = *(bh8*)(Bs + (wn * 64 + ni * 16 + l15) * 40 + quad * 8);
    #pragma unroll
    for (int mi = 0; mi < 4; ++mi)
      #pragma unroll
      for (int ni = 0; ni < 4; ++ni)
        acc[mi][ni] = __builtin_amdgcn_mfma_f32_16x16x32_bf16(af[mi], bfv[ni], acc[mi][ni], 0, 0, 0);
  }
  #pragma unroll
  for (int mi = 0; mi < 4; ++mi)
    #pragma unroll
    for (int ni = 0; ni < 4; ++ni)
      #pragma unroll
      for (int r = 0; r < 4; ++r) {
        int mg = m0 + wm * 64 + mi * 16 + quad * 4 + r;
        int ng = n0 + wn * 64 + ni * 16 + l15;
        C[mg * ldC + ng] = (ushort_t)f2bf(acc[mi][ni][r]);
      }
}

// cast section address computation (shared by the x2-unrolled loop)
__device__ __forceinline__ const float* cast_src(
    int i, const float* __restrict__ q, const float* __restrict__ xin,
    const float* __restrict__ addk, const float* __restrict__ Wval,
    const float* __restrict__ Wattn, ushort_t* __restrict__ arena,
    ushort_t** dst)
{
  const float* src; int e;
  if (i < 65536)        { src = q    + i * 4;            *dst = arena + i * 4; }
  else if (i < 916352)  { e = i - 65536;  src = xin  + e * 4; *dst = arena + 262144  + e * 4; }
  else if (i < 932736)  { e = i - 916352; src = addk + e * 4; *dst = arena + 3665408 + e * 4; }
  else if (i < 1194880) {                     // Wcat: [Wv1 row | Wv2 row]
    e = i - 932736; int el = e * 4;           // el in [0, 1048576)
    int h = el >> 17, r = el & 131071;
    int c = r >> 9, k = r & 511;
    src = Wval + (2 * h + (k >> 8)) * 65536 + c * 256 + (k & 255);
    *dst = arena + 3730944 + el;
  }
  else {                                      // Wattn level mats 0..31
    e = i - 1194880;
    src = Wattn + e * 4;
    *dst = arena + 6352384 + e * 4;
  }
  return src;
}

// ---------------------------------------------------------------------------
// FUSED A (R10 form, frozen).
// ---------------------------------------------------------------------------
__global__ __launch_bounds__(256) void k_fused_cast_off(
    const float* __restrict__ q, const float* __restrict__ xin,
    const float* __restrict__ addk, const float* __restrict__ Wval,
    const float* __restrict__ Wattn, ushort_t* __restrict__ arena,
    const float* __restrict__ Woff, const float* __restrict__ boff,
    const float* __restrict__ refpts, const int* __restrict__ shapes,
    const int* __restrict__ lvlst, int* __restrict__ fidx,
    ushort_t* __restrict__ tmp)
{
  __shared__ __align__(16) char smem[20480];
  if (blockIdx.x >= 96) {
    const int total4 = 1719168;
    const int S = 1952 * 256;
    for (int i = (blockIdx.x - 96) * 256 + threadIdx.x; i < total4; i += 2 * S) {
      ushort_t* d1; const float* s1 = cast_src(i, q, xin, addk, Wval, Wattn, arena, &d1);
      float4 v1 = *(const float4*)s1;
      int i2 = i + S;
      ushort_t* d2 = nullptr; float4 v2 = v1;
      if (i2 < total4) {
        const float* s2 = cast_src(i2, q, xin, addk, Wval, Wattn, arena, &d2);
        v2 = *(const float4*)s2;
      }
      ushort4 o1; o1.x = f2bf(v1.x); o1.y = f2bf(v1.y); o1.z = f2bf(v1.z); o1.w = f2bf(v1.w);
      *(ushort4*)d1 = o1;
      if (i2 < total4) {
        ushort4 o2; o2.x = f2bf(v2.x); o2.y = f2bf(v2.y); o2.z = f2bf(v2.z); o2.w = f2bf(v2.w);
        *(ushort4*)d2 = o2;
      }
    }
  } else if (blockIdx.x >= 64) {
    int e = blockIdx.x - 64;                   // 32 blocks: (2,2,8) flattened
    int h = e >> 2, rem = e & 3, my = rem >> 1, nx = rem & 1;
    gemm_abt_f32in(smem, addk, Wattn + (h * 4 + 4) * 65536, tmp + h * 65536,
                   256, 256, 256, 256, my * 128, nx * 128);
  } else {
    float(*As)[65] = (float(*)[65])smem;
    float(*Bs)[65] = (float(*)[65])(smem + 16 * 65 * 4);
    int e = blockIdx.x;
    int nx = e & 3, my = e >> 2;
    int m0 = my * 64, n0 = nx * 64;
    int t = threadIdx.x;
    int tm = t & 15, tn = t >> 4;
    int lr = t >> 4, lc = t & 15;
    float acc[4][4] = {};
    float qa[4], wb[4];
    #pragma unroll
    for (int i = 0; i < 4; ++i) {
      int r = lr + i * 16;
      qa[i] = q[(m0 + r) * 256 + lc];
      wb[i] = Woff[(n0 + r) * 256 + lc];
    }
    for (int k0 = 0; k0 < 256; k0 += 16) {
      if (k0) __syncthreads();
      #pragma unroll
      for (int i = 0; i < 4; ++i) {
        int r = lr + i * 16;
        As[lc][r] = qa[i];
        Bs[lc][r] = wb[i];
      }
      if (k0 + 16 < 256) {
        #pragma unroll
        for (int i = 0; i < 4; ++i) {
          int r = lr + i * 16;
          qa[i] = q[(m0 + r) * 256 + k0 + 16 + lc];
          wb[i] = Woff[(n0 + r) * 256 + k0 + 16 + lc];
        }
      }
      __syncthreads();
      #pragma unroll
      for (int k = 0; k < 16; ++k) {
        float a[4], b[4];
        #pragma unroll
        for (int i = 0; i < 4; ++i) a[i] = As[k][tm * 4 + i];
        #pragma unroll
        for (int j = 0; j < 4; ++j) b[j] = Bs[k][tn * 4 + j];
        #pragma unroll
        for (int i = 0; i < 4; ++i)
          #pragma unroll
          for (int j = 0; j < 4; ++j) acc[i][j] += a[i] * b[j];
      }
    }
    #pragma unroll
    for (int i = 0; i < 4; ++i) {
      int b = m0 + tm * 4 + i;
      #pragma unroll
      for (int jp = 0; jp < 2; ++jp) {
        int tt = ((n0 + tn * 4) >> 1) + jp;
        int l = (tt >> 2) & 3;
        float off0 = acc[i][jp * 2]     + boff[2 * tt];
        float off1 = acc[i][jp * 2 + 1] + boff[2 * tt + 1];
        int Hi = shapes[2 * l], Wi = shapes[2 * l + 1];
        float Hf = (float)Hi, Wf = (float)Wi;
        float r0 = refpts[b * 8 + 2 * l], r1 = refpts[b * 8 + 2 * l + 1];
        float l0 = fminf(fmaxf(r0 + off0 / Wf, 0.f), 0.999f);
        float l1 = fminf(fmaxf(r1 + off1 / Hf, 0.f), 0.999f);
        int i0 = (int)(l0 * Hf);
        int i1 = (int)(l1 * Wf);
        fidx[b * 128 + tt] = i0 + i1 * Hi + lvlst[l];
      }
    }
  }
}

// ---------------------------------------------------------------------------
// MFMA level-attention body — R5 (dbuf + reg prefetch), frozen.
// ---------------------------------------------------------------------------
__device__ __forceinline__ void attn_mfma_body(
    char* smemc,
    const ushort_t* __restrict__ qbf, const ushort_t* __restrict__ xbf,
    const ushort_t* __restrict__ Wlvl, const int* __restrict__ fidx,
    float* __restrict__ attnP, int bx)
{
  unsigned* Bs0 = (unsigned*)smemc;
  unsigned* Bs1 = (unsigned*)(smemc + 8704);
  ushort_t* As0 = (ushort_t*)(smemc + 17408);
  ushort_t* As1 = (ushort_t*)(smemc + 26624);
  int* fis = (int*)(smemc + 35840);
  float* Nlds = (float*)smemc;                   // overlay, stride 68

  int h = bx >> 8, l = (bx >> 6) & 3, g = bx & 63;
  int ch = g & 3, g2 = g >> 2;
  int p = g2 >> 2, tg = g2 & 3;
  int c0 = ch * 64;
  int t = threadIdx.x;
  int lane = t & 63, w = t >> 6;
  int quad = lane >> 4, l15 = lane & 15;
  int qcol = p * 4 + tg;
  fis[t] = fidx[(tg * 256 + t) * 128 + h * 16 + l * 4 + p];
  __syncthreads();
  f4 acc[4];
  #pragma unroll
  for (int mi = 0; mi < 4; ++mi) acc[mi] = (f4)0.f;

  int cl = t & 63, sg = t >> 6;
  int uu = t >> 2, jj0 = (t & 3) * 16;
  const ushort_t* qrow = qbf + (uu * 16 + qcol) * 256 + jj0;

  unsigned vv[16];
  u4 a0, a1;
  #pragma unroll
  for (int rr = 0; rr < 16; ++rr)
    vv[rr] = xbf[fis[sg * 16 + rr] * 256 + c0 + cl];
  { const u4* src = (const u4*)qrow; a0 = src[0]; a1 = src[1]; }
  #pragma unroll
  for (int i = 0; i < 4; ++i) {
    uint2 w2; w2.x = vv[i * 4] | (vv[i * 4 + 1] << 16);
    w2.y = vv[i * 4 + 2] | (vv[i * 4 + 3] << 16);
    *(uint2*)&Bs0[cl * 34 + sg * 8 + i * 2] = w2;
  }
  { u4* dst = (u4*)(As0 + uu * 72 + jj0); dst[0] = a0; dst[1] = a1; }
  #pragma unroll
  for (int rr = 0; rr < 16; ++rr)
    vv[rr] = xbf[fis[64 + sg * 16 + rr] * 256 + c0 + cl];
  { const u4* src = (const u4*)(qrow + 64); a0 = src[0]; a1 = src[1]; }
  __syncthreads();                               // buf0 visible

  #pragma unroll
  for (int jt = 0; jt < 4; ++jt) {
    unsigned* Bc = (jt & 1) ? Bs1 : Bs0;
    ushort_t* Ac = (jt & 1) ? As1 : As0;
    if (jt < 3) {
      unsigned* Bn = (jt & 1) ? Bs0 : Bs1;
      ushort_t* An = (jt & 1) ? As0 : As1;
      #pragma unroll
      for (int i = 0; i < 4; ++i) {
        uint2 w2; w2.x = vv[i * 4] | (vv[i * 4 + 1] << 16);
        w2.y = vv[i * 4 + 2] | (vv[i * 4 + 3] << 16);
        *(uint2*)&Bn[cl * 34 + sg * 8 + i * 2] = w2;
      }
      { u4* dst = (u4*)(An + uu * 72 + jj0); dst[0] = a0; dst[1] = a1; }
      if (jt < 2) {
        #pragma unroll
        for (int rr = 0; rr < 16; ++rr)
          vv[rr] = xbf[fis[(jt + 2) * 64 + sg * 16 + rr] * 256 + c0 + cl];
        const u4* src = (const u4*)(qrow + (jt + 2) * 64);
        a0 = src[0]; a1 = src[1];
      }
    }
    #pragma unroll
    for (int ks = 0; ks < 2; ++ks) {
      bh8 af[4], bfv;
      #pragma unroll
      for (int mi = 0; mi < 4; ++mi)
        af[mi] = *(bh8*)(Ac + (mi * 16 + l15) * 72 + ks * 32 + quad * 8);
      {
        const unsigned* bp = &Bc[(w * 16 + l15) * 34 + ks * 16 + quad * 4];
        uint2 b0 = *(const uint2*)bp;
        uint2 b1 = *(const uint2*)(bp + 2);
        u4 bb; bb.x = b0.x; bb.y = b0.y; bb.z = b1.x; bb.w = b1.y;
        bfv = __builtin_bit_cast(bh8, bb);
      }
      #pragma unroll
      for (int mi = 0; mi < 4; ++mi)
        acc[mi] = __builtin_amdgcn_mfma_f32_16x16x32_bf16(af[mi], bfv, acc[mi], 0, 0, 0);
    }
    if (jt < 3) __syncthreads();
  }
  __syncthreads();
  #pragma unroll
  for (int mi = 0; mi < 4; ++mi)
    *(f4*)&Nlds[(w * 16 + l15) * 68 + mi * 16 + quad * 4] = acc[mi];
  __syncthreads();
  {
    int a = t >> 6, u = t & 63;
    const ushort_t* Wr = Wlvl + (h * 4 + l) * 65536 + (a * 64 + u) * 256 + c0;
    float s = 0.f;
    #pragma unroll
    for (int cc = 0; cc < 8; ++cc) {
      u4 wv = *(const u4*)(Wr + cc * 8);
      int cb = cc * 8;
      s += __uint_as_float(wv.x << 16)         * Nlds[(cb + 0) * 68 + u];
      s += __uint_as_float(wv.x & 0xffff0000u) * Nlds[(cb + 1) * 68 + u];
      s += __uint_as_float(wv.y << 16)         * Nlds[(cb + 2) * 68 + u];
      s += __uint_as_float(wv.y & 0xffff0000u) * Nlds[(cb + 3) * 68 + u];
      s += __uint_as_float(wv.z << 16)         * Nlds[(cb + 4) * 68 + u];
      s += __uint_as_float(wv.z & 0xffff0000u) * Nlds[(cb + 5) * 68 + u];
      s += __uint_as_float(wv.w << 16)         * Nlds[(cb + 6) * 68 + u];
      s += __uint_as_float(wv.w & 0xffff0000u) * Nlds[(cb + 7) * 68 + u];
    }
    attnP[ch * 131072 + (h * 16 + l * 4 + a) * 1024 + u * 16 + qcol] = s;
  }
}

// ---------------------------------------------------------------------------
// FUSED C — **MEASUREMENT ROUND**: body executed TWICE (idempotent; R4
// pattern). Δdur vs R10 = kernel C's current marginal cost; top-5 row gives
// its post-R5/R8 counters (VGPR / Occupancy / HBM) to target R12 precisely.
// ---------------------------------------------------------------------------
__global__ __launch_bounds__(256) void k_fused_attn(
    const ushort_t* __restrict__ qbf, const ushort_t* __restrict__ xbf,
    const ushort_t* __restrict__ Wlvl, const int* __restrict__ fidx,
    float* __restrict__ attnP,
    const ushort_t* __restrict__ tmp, float* __restrict__ attn)
{
  __shared__ __align__(16) char smem[36864];
  int bx = blockIdx.x;
  for (int rep = 0; rep < 2; ++rep) {
    if (rep) { asm volatile("" ::: "memory"); __syncthreads(); }
    if (bx >= 256) {
      attn_mfma_body(smem, qbf, xbf, Wlvl, fidx, attnP, bx - 256);
    } else {
      int e = bx;                              // 256 blocks: (16,2,8) flattened
      int h = e >> 5, rem = e & 31, my = rem >> 4, nx = rem & 15;
      gemm_abt_12864(smem, tmp + h * 65536, qbf, attn + h * 278528 + 16384,
                     256, 256, 1024, 256, my * 128, nx * 64);
    }
  }
}

// ---------------------------------------------------------------------------
// softmax (R9 form, frozen): 512 threads, 32 row-groups x 9 rows.
// ---------------------------------------------------------------------------
__global__ __launch_bounds__(512) void k_softmax(
    float* __restrict__ attn, const float* __restrict__ attnP,
    ushort_t* __restrict__ attn2bf, float* __restrict__ s1, float* __restrict__ s2)
{
  __shared__ float red[32][17];
  int h = blockIdx.y;
  int bl = threadIdx.x & 15;
  int b = blockIdx.x * 16 + bl;
  int rg = threadIdx.x >> 4;                   // 0..31
  const int R0 = rg * 9;
  float* col = attn + h * 278528 + b;
  float v[9];
  float m = -1e30f;
  #pragma unroll
  for (int i = 0; i < 9; ++i) {
    int r = R0 + i;
    float x;
    if (r < 16) {
      int idx = (h * 16 + r) * 1024 + b;
      x = attnP[idx] + attnP[131072 + idx] + attnP[262144 + idx] + attnP[393216 + idx];
    } else if (r < 272) {
      x = col[r * 1024];
    } else {
      x = -1e30f;
    }
    v[i] = x;
    m = fmaxf(m, x);
  }
  red[rg][bl] = m;
  __syncthreads();
  #pragma unroll
  for (int j = 0; j < 32; ++j) m = fmaxf(m, red[j][bl]);
  float sum = 0.f;
  #pragma unroll
  for (int i = 0; i < 9; ++i) { v[i] = expf(v[i] - m); sum += v[i]; }
  __syncthreads();
  red[rg][bl] = sum;
  __syncthreads();
  float tot = 0.f;
  #pragma unroll
  for (int j = 0; j < 32; ++j) tot += red[j][bl];
  float inv = 1.f / tot;
  #pragma unroll
  for (int i = 0; i < 9; ++i) {
    int r = R0 + i;
    float x = v[i] * inv;
    if (r < 16) col[r * 1024] = x;
    else if (r < 272) attn2bf[h * 262144 + (r - 16) * 1024 + b] = f2bf(x);
  }
  __syncthreads();
  if (rg < 2) {
    float sa = 0.f;
    #pragma unroll
    for (int i = 0; i < 9; ++i) {
      int r = R0 + i;
      if (r < 16) sa += v[i];
    }
    red[rg][bl] = sa;
  }
  __syncthreads();
  if (rg == 0) {
    float sn = (red[0][bl] + red[1][bl]) * inv;
    s1[h * 1024 + b] = sn;
    s2[h * 1024 + b] = 1.f - sn;
  }
}

// ---------------------------------------------------------------------------
// FUSED D (R8 form, frozen): TN 128x64 (0..255) + kbar gather (256..1279).
// ---------------------------------------------------------------------------
__global__ __launch_bounds__(256) void k_fused_kbar_tn(
    const ushort_t* __restrict__ xbf, const float* __restrict__ attn,
    const int* __restrict__ fidx, const ushort_t* __restrict__ attn2,
    const ushort_t* __restrict__ addk, ushort_t* __restrict__ kabar)
{
  __shared__ __align__(16) unsigned Asu[128 * 20];
  __shared__ __align__(16) unsigned Bsu[64 * 20];
  if (blockIdx.x >= 256) {
    int bb = blockIdx.x - 256;
    int h = bb >> 7, b0 = (bb & 127) * 8;
    int t = threadIdx.x;
    int qi = t >> 5, oct = t & 31;
    int b = b0 + qi;
    float aw[16]; int rowv[16];
    #pragma unroll
    for (int r = 0; r < 16; ++r) {
      aw[r]   = attn[(h * 272 + r) * 1024 + b];
      rowv[r] = fidx[b * 128 + h * 16 + r];
    }
    float sacc[8] = {};
    u4 va[8];
    #pragma unroll
    for (int r = 0; r < 8; ++r) va[r] = *(const u4*)(xbf + rowv[r] * 256 + oct * 8);
    #pragma unroll
    for (int r = 0; r < 8; ++r) {
      u4 v = va[r]; float w = aw[r];
      sacc[0] += w * __uint_as_float(v.x << 16);
      sacc[1] += w * __uint_as_float(v.x & 0xffff0000u);
      sacc[2] += w * __uint_as_float(v.y << 16);
      sacc[3] += w * __uint_as_float(v.y & 0xffff0000u);
      sacc[4] += w * __uint_as_float(v.z << 16);
      sacc[5] += w * __uint_as_float(v.z & 0xffff0000u);
      sacc[6] += w * __uint_as_float(v.w << 16);
      sacc[7] += w * __uint_as_float(v.w & 0xffff0000u);
    }
    #pragma unroll
    for (int r = 0; r < 8; ++r) va[r] = *(const u4*)(xbf + rowv[8 + r] * 256 + oct * 8);
    #pragma unroll
    for (int r = 0; r < 8; ++r) {
      u4 v = va[r]; float w = aw[8 + r];
      sacc[0] += w * __uint_as_float(v.x << 16);
      sacc[1] += w * __uint_as_float(v.x & 0xffff0000u);
      sacc[2] += w * __uint_as_float(v.y << 16);
      sacc[3] += w * __uint_as_float(v.y & 0xffff0000u);
      sacc[4] += w * __uint_as_float(v.z << 16);
      sacc[5] += w * __uint_as_float(v.z & 0xffff0000u);
      sacc[6] += w * __uint_as_float(v.w << 16);
      sacc[7] += w * __uint_as_float(v.w & 0xffff0000u);
    }
    u4 o;
    o.x = (unsigned)f2bf(sacc[0]) | ((unsigned)f2bf(sacc[1]) << 16);
    o.y = (unsigned)f2bf(sacc[2]) | ((unsigned)f2bf(sacc[3]) << 16);
    o.z = (unsigned)f2bf(sacc[4]) | ((unsigned)f2bf(sacc[5]) << 16);
    o.w = (unsigned)f2bf(sacc[6]) | ((unsigned)f2bf(sacc[7]) << 16);
    *(u4*)(kabar + (h * 1024 + b) * 512 + oct * 8) = o;
  } else {
    // TN 128x64: C[h][m0+..][256+n0+..] = sum_k attn2[h][k][m] * addk[k][n]
    int e = blockIdx.x;                        // 256 blocks: (8h, 8my, 4nx)
    int h = e >> 5, rem = e & 31, my = rem >> 2, nx = rem & 3;
    const ushort_t* A = attn2 + h * 262144;    // [k*1024 + m]
    const ushort_t* B = addk;                  // [k*256 + n]
    ushort_t* C = kabar + h * 524288;
    int m0 = my * 128, n0 = nx * 64;
    int t = threadIdx.x;
    int lane = t & 63, w = t >> 6;
    int quad = lane >> 4, l15 = lane & 15;
    int wm = w >> 1, wn = w & 1;
    f4 acc[4][2];
    #pragma unroll
    for (int mi = 0; mi < 4; ++mi)
      #pragma unroll
      for (int ni = 0; ni < 2; ++ni) acc[mi][ni] = (f4)0.f;
    int colA = t & 127, halfA = t >> 7;        // A: 128 rows, kpp halfA*4+i
    int colB = t & 63,  grpB  = t >> 6;        // B: 64 rows,  kpp grpB*2+i
    for (int k0 = 0; k0 < 256; k0 += 32) {
      if (k0) __syncthreads();
      #pragma unroll
      for (int i = 0; i < 4; ++i) {
        int kpp = halfA * 4 + i, kk = k0 + kpp * 4;
        unsigned x0 = A[(kk + 0) * 1024 + m0 + colA], x1 = A[(kk + 1) * 1024 + m0 + colA];
        unsigned x2 = A[(kk + 2) * 1024 + m0 + colA], x3 = A[(kk + 3) * 1024 + m0 + colA];
        uint2 va; va.x = x0 | (x1 << 16); va.y = x2 | (x3 << 16);
        *(uint2*)&Asu[colA * 20 + kpp * 2] = va;
      }
      #pragma unroll
      for (int i = 0; i < 2; ++i) {
        int kpp = grpB * 2 + i, kk = k0 + kpp * 4;
        unsigned y0 = B[(kk + 0) * 256 + n0 + colB], y1 = B[(kk + 1) * 256 + n0 + colB];
        unsigned y2 = B[(kk + 2) * 256 + n0 + colB], y3 = B[(kk + 3) * 256 + n0 + colB];
        uint2 vb; vb.x = y0 | (y1 << 16); vb.y = y2 | (y3 << 16);
        *(uint2*)&Bsu[colB * 20 + kpp * 2] = vb;
      }
      __syncthreads();
      bh8 af[4], bf2[2];
      #pragma unroll
      for (int mi = 0; mi < 4; ++mi)
        af[mi] = *(bh8*)((const ushort_t*)Asu + (wm * 64 + mi * 16 + l15) * 40 + quad * 8);
      #pragma unroll
      for (int ni = 0; ni < 2; ++ni)
        bf2[ni] = *(bh8*)((const ushort_t*)Bsu + (wn * 32 + ni * 16 + l15) * 40 + quad * 8);
      #pragma unroll
      for (int mi = 0; mi < 4; ++mi)
        #pragma unroll
        for (int ni = 0; ni < 2; ++ni)
          acc[mi][ni] = __builtin_amdgcn_mfma_f32_16x16x32_bf16(af[mi], bf2[ni], acc[mi][ni], 0, 0, 0);
    }
    #pragma unroll
    for (int mi = 0; mi < 4; ++mi)
      #pragma unroll
      for (int ni = 0; ni < 2; ++ni)
        #pragma unroll
        for (int r = 0; r < 4; ++r) {
          int mg = m0 + wm * 64 + mi * 16 + quad * 4 + r;
          int ng = n0 + wn * 32 + ni * 16 + l15;
          C[mg * 512 + 256 + ng] = f2bf(acc[mi][ni][r]);
        }
  }
}

// ---------------------------------------------------------------------------
// gemm_val (R9 form, frozen): 128x64 tiles -> 256 blocks.
// ---------------------------------------------------------------------------
__global__ __launch_bounds__(256) void gemm_val_k(
    const ushort_t* __restrict__ kabar, const ushort_t* __restrict__ Wcat,
    float* __restrict__ Y)
{
  __shared__ __align__(16) char smem[20480];
  int h = blockIdx.z;
  gemm_abt_12864(smem, kabar + h * 524288, Wcat + h * 131072, Y + h * 262144,
                 512, 512, 256, 512, blockIdx.y * 128, blockIdx.x * 64);
}

// ------------------------------- final combine ------------------------------
__global__ __launch_bounds__(256) void k_combine(
    const float* __restrict__ q, const float* __restrict__ Wmix,
    const float* __restrict__ Y,
    const float* __restrict__ s1, const float* __restrict__ s2,
    const float* __restrict__ bval, float* __restrict__ out)
{
  int b = blockIdx.x, c = threadIdx.x;
  float w[9];
  float m = -1e30f;
  #pragma unroll
  for (int j = 0; j < 9; ++j) { w[j] = Wmix[c * 9 + j]; m = fmaxf(m, w[j]); }
  float tot = 0.f;
  #pragma unroll
  for (int j = 0; j < 9; ++j) { w[j] = expf(w[j] - m); tot += w[j]; }
  float inv = 1.f / tot;
  float res = q[b * 256 + c] * w[8] * inv;
  #pragma unroll
  for (int hh = 0; hh < 8; ++hh) {
    float y = Y[(hh * 1024 + b) * 256 + c]
            + s1[hh * 1024 + b] * bval[(2 * hh) * 256 + c]
            + s2[hh * 1024 + b] * bval[(2 * hh + 1) * 256 + c];
    res += w[hh] * inv * y;
  }
  out[b * 256 + c] = res;
}

extern "C" void kernel_launch(void* const* d_in, const int* in_sizes, int n_in,
                              void* d_out, int out_size, void* d_ws, size_t ws_size,
                              hipStream_t stream) {
  (void)in_sizes; (void)n_in; (void)out_size; (void)ws_size;
  const float* q      = (const float*)d_in[0];
  const float* refpts = (const float*)d_in[1];
  const float* xin    = (const float*)d_in[2];
  const int*   shapes = (const int*)d_in[3];
  const float* addk   = (const float*)d_in[4];
  const int*   lvlst  = (const int*)d_in[5];
  const float* Woff   = (const float*)d_in[6];
  const float* boff   = (const float*)d_in[7];
  const float* Wattn  = (const float*)d_in[8];
  const float* Wval   = (const float*)d_in[9];
  const float* bval   = (const float*)d_in[10];
  const float* Wmix   = (const float*)d_in[11];
  float* out = (float*)d_out;
  float* ws  = (float*)d_ws;

  int*   fidx    = (int*)ws;                  // [0, 131072)
  float* s1      = ws + 393216;               // 8192
  float* s2      = ws + 401408;               // 8192
  float* attn    = ws + 409600;               // 8*272*1024 fp32 (dead after fused_d)
  float* Y       = ws + 409600;               // overlays attn (written by gemm_val_k)
  ushort_t* arena = (ushort_t*)(ws + 2637824);
  ushort_t* q_bf     = arena;                 // 262144
  ushort_t* xin_bf   = arena + 262144;        // 3403264
  ushort_t* addk_bf  = arena + 3665408;       // 65536
  ushort_t* Wcat_bf  = arena + 3730944;       // 1048576 (stride 131072/head)
  ushort_t* Wlvl_bf  = arena + 6352384;       // 2097152
  ushort_t* tmp_bf   = arena + 8449536;       // 524288
  ushort_t* attn2_bf = arena + 8973824;       // 2097152
  ushort_t* kabar_bf = arena + 11070976;      // 4194304 (8*1024*512)
  float* attnP = (float*)(arena + 15265280);  // 4 * 131072 f (per-ch partials)

  k_fused_cast_off<<<2048, 256, 0, stream>>>(q, xin, addk, Wval, Wattn, arena,
                                             Woff, boff, refpts, shapes, lvlst,
                                             fidx, tmp_bf);
  k_fused_attn<<<2304, 256, 0, stream>>>(q_bf, xin_bf, Wlvl_bf, fidx, attnP,
                                         tmp_bf, attn);
  k_softmax<<<dim3(64, 8), 512, 0, stream>>>(attn, attnP, attn2_bf, s1, s2);
  k_fused_kbar_tn<<<1280, 256, 0, stream>>>(xin_bf, attn, fidx, attn2_bf,
                                            addk_bf, kabar_bf);
  gemm_val_k<<<dim3(4, 8, 8), 256, 0, stream>>>(kabar_bf, Wcat_bf, Y);
  k_combine<<<1024, 256, 0, stream>>>(q, Wmix, Y, s1, s2, bval, out);
}

// Round 13
// 186.359 us; speedup vs baseline: 1.0541x; 1.0541x over previous
//
#include <hip/hip_runtime.h>

typedef unsigned short ushort_t;
typedef __attribute__((ext_vector_type(8))) short bh8;     // 8 bf16 (4 VGPRs)
typedef __attribute__((ext_vector_type(4))) float f4;      // 4 fp32 acc
typedef __attribute__((ext_vector_type(4))) unsigned int u4;

__device__ __forceinline__ ushort_t f2bf(float f) {
  unsigned u = __float_as_uint(f);
  return (ushort_t)((u + 0x7FFFu + ((u >> 16) & 1u)) >> 16);
}
__device__ __forceinline__ float bf2f(ushort_t v) {
  return __uint_as_float(((unsigned)v) << 16);
}

// ---------------------------------------------------------------------------
// bf16 MFMA GEMM core, abt form, LDS passed in (20480 B: As 10240 + Bs 10240)
// Register double-buffered staging (R1).
// ---------------------------------------------------------------------------
template <typename OutT>
__device__ __forceinline__ void gemm_abt_core(
    char* smem,
    const ushort_t* __restrict__ A, const ushort_t* __restrict__ B,
    OutT* __restrict__ C, int ldA, int ldB, int ldC, int K, int m0, int n0)
{
  ushort_t* As = (ushort_t*)smem;
  ushort_t* Bs = (ushort_t*)(smem + 10240);
  int t = threadIdx.x;
  int lane = t & 63, w = t >> 6;
  int quad = lane >> 4, l15 = lane & 15;
  int wm = w >> 1, wn = w & 1;
  f4 acc[4][4];
  #pragma unroll
  for (int mi = 0; mi < 4; ++mi)
    #pragma unroll
    for (int ni = 0; ni < 4; ++ni) acc[mi][ni] = (f4)0.f;
  int row = t >> 1, kh = (t & 1) * 16;
  const ushort_t* pa = A + (m0 + row) * ldA + kh;
  const ushort_t* pb = B + (n0 + row) * ldB + kh;
  u4 va0 = *(const u4*)(pa);     u4 va1 = *(const u4*)(pa + 8);
  u4 vb0 = *(const u4*)(pb);     u4 vb1 = *(const u4*)(pb + 8);
  for (int k0 = 0; k0 < K; k0 += 32) {
    if (k0) __syncthreads();
    {
      u4* da = (u4*)(As + row * 40 + kh); da[0] = va0; da[1] = va1;
      u4* db = (u4*)(Bs + row * 40 + kh); db[0] = vb0; db[1] = vb1;
    }
    if (k0 + 32 < K) {
      va0 = *(const u4*)(pa + k0 + 32); va1 = *(const u4*)(pa + k0 + 40);
      vb0 = *(const u4*)(pb + k0 + 32); vb1 = *(const u4*)(pb + k0 + 40);
    }
    __syncthreads();
    bh8 af[4], bfv[4];
    #pragma unroll
    for (int mi = 0; mi < 4; ++mi)
      af[mi] = *(bh8*)(As + (wm * 64 + mi * 16 + l15) * 40 + quad * 8);
    #pragma unroll
    for (int ni = 0; ni < 4; ++ni)
      bfv[ni] = *(bh8*)(Bs + (wn * 64 + ni * 16 + l15) * 40 + quad * 8);
    #pragma unroll
    for (int mi = 0; mi < 4; ++mi)
      #pragma unroll
      for (int ni = 0; ni < 4; ++ni)
        acc[mi][ni] = __builtin_amdgcn_mfma_f32_16x16x32_bf16(af[mi], bfv[ni], acc[mi][ni], 0, 0, 0);
  }
  #pragma unroll
  for (int mi = 0; mi < 4; ++mi)
    #pragma unroll
    for (int ni = 0; ni < 4; ++ni)
      #pragma unroll
      for (int r = 0; r < 4; ++r) {
        int mg = m0 + wm * 64 + mi * 16 + quad * 4 + r;
        int ng = n0 + wn * 64 + ni * 16 + l15;
        if constexpr (sizeof(OutT) == 4) C[mg * ldC + ng] = acc[mi][ni][r];
        else C[mg * ldC + ng] = (OutT)f2bf(acc[mi][ni][r]);
      }
}

// ---------------------------------------------------------------------------
// 128x64-tile variant (R5; R9: also used by gemm_val_k). LDS 15360 B.
// ---------------------------------------------------------------------------
__device__ __forceinline__ void gemm_abt_12864(
    char* smem,
    const ushort_t* __restrict__ A, const ushort_t* __restrict__ B,
    float* __restrict__ C, int ldA, int ldB, int ldC, int K, int m0, int n0)
{
  ushort_t* As = (ushort_t*)smem;
  ushort_t* Bs = (ushort_t*)(smem + 10240);
  int t = threadIdx.x;
  int lane = t & 63, w = t >> 6;
  int quad = lane >> 4, l15 = lane & 15;
  int wm = w >> 1, wn = w & 1;
  f4 acc[4][2];
  #pragma unroll
  for (int mi = 0; mi < 4; ++mi)
    #pragma unroll
    for (int ni = 0; ni < 2; ++ni) acc[mi][ni] = (f4)0.f;
  int rowA = t >> 1, khA = (t & 1) * 16;
  int rowB = t >> 2, khB = (t & 3) * 8;
  const ushort_t* pa = A + (m0 + rowA) * ldA + khA;
  const ushort_t* pb = B + (n0 + rowB) * ldB + khB;
  u4 va0 = *(const u4*)(pa); u4 va1 = *(const u4*)(pa + 8);
  u4 vb0 = *(const u4*)(pb);
  for (int k0 = 0; k0 < K; k0 += 32) {
    if (k0) __syncthreads();
    {
      u4* da = (u4*)(As + rowA * 40 + khA); da[0] = va0; da[1] = va1;
      u4* db = (u4*)(Bs + rowB * 40 + khB); db[0] = vb0;
    }
    if (k0 + 32 < K) {
      va0 = *(const u4*)(pa + k0 + 32); va1 = *(const u4*)(pa + k0 + 40);
      vb0 = *(const u4*)(pb + k0 + 32);
    }
    __syncthreads();
    bh8 af[4], bf2[2];
    #pragma unroll
    for (int mi = 0; mi < 4; ++mi)
      af[mi] = *(bh8*)(As + (wm * 64 + mi * 16 + l15) * 40 + quad * 8);
    #pragma unroll
    for (int ni = 0; ni < 2; ++ni)
      bf2[ni] = *(bh8*)(Bs + (wn * 32 + ni * 16 + l15) * 40 + quad * 8);
    #pragma unroll
    for (int mi = 0; mi < 4; ++mi)
      #pragma unroll
      for (int ni = 0; ni < 2; ++ni)
        acc[mi][ni] = __builtin_amdgcn_mfma_f32_16x16x32_bf16(af[mi], bf2[ni], acc[mi][ni], 0, 0, 0);
  }
  #pragma unroll
  for (int mi = 0; mi < 4; ++mi)
    #pragma unroll
    for (int ni = 0; ni < 2; ++ni)
      #pragma unroll
      for (int r = 0; r < 4; ++r) {
        int mg = m0 + wm * 64 + mi * 16 + quad * 4 + r;
        int ng = n0 + wn * 32 + ni * 16 + l15;
        C[mg * ldC + ng] = acc[mi][ni][r];
      }
}

// ---------------------------------------------------------------------------
// fp32-input variant (R7 form: no register prefetch).
// ---------------------------------------------------------------------------
__device__ __forceinline__ void gemm_abt_f32in(
    char* smem,
    const float* __restrict__ A, const float* __restrict__ B,
    ushort_t* __restrict__ C, int ldA, int ldB, int ldC, int K, int m0, int n0)
{
  ushort_t* As = (ushort_t*)smem;
  ushort_t* Bs = (ushort_t*)(smem + 10240);
  int t = threadIdx.x;
  int lane = t & 63, w = t >> 6;
  int quad = lane >> 4, l15 = lane & 15;
  int wm = w >> 1, wn = w & 1;
  f4 acc[4][4];
  #pragma unroll
  for (int mi = 0; mi < 4; ++mi)
    #pragma unroll
    for (int ni = 0; ni < 4; ++ni) acc[mi][ni] = (f4)0.f;
  int row = t >> 1, kh = (t & 1) * 16;
  const float* pa = A + (m0 + row) * ldA + kh;
  const float* pb = B + (n0 + row) * ldB + kh;
  for (int k0 = 0; k0 < K; k0 += 32) {
    if (k0) __syncthreads();
    {
      ushort_t* da = As + row * 40 + kh;
      ushort_t* db = Bs + row * 40 + kh;
      #pragma unroll
      for (int i = 0; i < 4; ++i) {
        float4 fa = *(const float4*)(pa + k0 + i * 4);
        float4 fb = *(const float4*)(pb + k0 + i * 4);
        ushort4 oa; oa.x = f2bf(fa.x); oa.y = f2bf(fa.y);
        oa.z = f2bf(fa.z); oa.w = f2bf(fa.w);
        *(ushort4*)(da + i * 4) = oa;
        ushort4 ob; ob.x = f2bf(fb.x); ob.y = f2bf(fb.y);
        ob.z = f2bf(fb.z); ob.w = f2bf(fb.w);
        *(ushort4*)(db + i * 4) = ob;
      }
    }
    __syncthreads();
    bh8 af[4], bfv[4];
    #pragma unroll
    for (int mi = 0; mi < 4; ++mi)
      af[mi] = *(bh8*)(As + (wm * 64 + mi * 16 + l15) * 40 + quad * 8);
    #pragma unroll
    for (int ni = 0; ni < 4; ++ni)
      bfv[ni] = *(bh8*)(Bs + (wn * 64 + ni * 16 + l15) * 40 + quad * 8);
    #pragma unroll
    for (int mi = 0; mi < 4; ++mi)
      #pragma unroll
      for (int ni = 0; ni < 4; ++ni)
        acc[mi][ni] = __builtin_amdgcn_mfma_f32_16x16x32_bf16(af[mi], bfv[ni], acc[mi][ni], 0, 0, 0);
  }
  #pragma unroll
  for (int mi = 0; mi < 4; ++mi)
    #pragma unroll
    for (int ni = 0; ni < 4; ++ni)
      #pragma unroll
      for (int r = 0; r < 4; ++r) {
        int mg = m0 + wm * 64 + mi * 16 + quad * 4 + r;
        int ng = n0 + wn * 64 + ni * 16 + l15;
        C[mg * ldC + ng] = (ushort_t)f2bf(acc[mi][ni][r]);
      }
}

// cast section address computation (shared by the x2-unrolled loop)
__device__ __forceinline__ const float* cast_src(
    int i, const float* __restrict__ q, const float* __restrict__ xin,
    const float* __restrict__ addk, const float* __restrict__ Wval,
    const float* __restrict__ Wattn, ushort_t* __restrict__ arena,
    ushort_t** dst)
{
  const float* src; int e;
  if (i < 65536)        { src = q    + i * 4;            *dst = arena + i * 4; }
  else if (i < 916352)  { e = i - 65536;  src = xin  + e * 4; *dst = arena + 262144  + e * 4; }
  else if (i < 932736)  { e = i - 916352; src = addk + e * 4; *dst = arena + 3665408 + e * 4; }
  else if (i < 1194880) {                     // Wcat: [Wv1 row | Wv2 row]
    e = i - 932736; int el = e * 4;           // el in [0, 1048576)
    int h = el >> 17, r = el & 131071;
    int c = r >> 9, k = r & 511;
    src = Wval + (2 * h + (k >> 8)) * 65536 + c * 256 + (k & 255);
    *dst = arena + 3730944 + el;
  }
  else {                                      // Wattn level mats 0..31
    e = i - 1194880;
    src = Wattn + e * 4;
    *dst = arena + 6352384 + e * 4;
  }
  return src;
}

// ---------------------------------------------------------------------------
// FUSED A (R10 form, frozen).
// ---------------------------------------------------------------------------
__global__ __launch_bounds__(256) void k_fused_cast_off(
    const float* __restrict__ q, const float* __restrict__ xin,
    const float* __restrict__ addk, const float* __restrict__ Wval,
    const float* __restrict__ Wattn, ushort_t* __restrict__ arena,
    const float* __restrict__ Woff, const float* __restrict__ boff,
    const float* __restrict__ refpts, const int* __restrict__ shapes,
    const int* __restrict__ lvlst, int* __restrict__ fidx,
    ushort_t* __restrict__ tmp)
{
  __shared__ __align__(16) char smem[20480];
  if (blockIdx.x >= 96) {
    const int total4 = 1719168;
    const int S = 1952 * 256;
    for (int i = (blockIdx.x - 96) * 256 + threadIdx.x; i < total4; i += 2 * S) {
      ushort_t* d1; const float* s1 = cast_src(i, q, xin, addk, Wval, Wattn, arena, &d1);
      float4 v1 = *(const float4*)s1;
      int i2 = i + S;
      ushort_t* d2 = nullptr; float4 v2 = v1;
      if (i2 < total4) {
        const float* s2 = cast_src(i2, q, xin, addk, Wval, Wattn, arena, &d2);
        v2 = *(const float4*)s2;
      }
      ushort4 o1; o1.x = f2bf(v1.x); o1.y = f2bf(v1.y); o1.z = f2bf(v1.z); o1.w = f2bf(v1.w);
      *(ushort4*)d1 = o1;
      if (i2 < total4) {
        ushort4 o2; o2.x = f2bf(v2.x); o2.y = f2bf(v2.y); o2.z = f2bf(v2.z); o2.w = f2bf(v2.w);
        *(ushort4*)d2 = o2;
      }
    }
  } else if (blockIdx.x >= 64) {
    int e = blockIdx.x - 64;                   // 32 blocks: (2,2,8) flattened
    int h = e >> 2, rem = e & 3, my = rem >> 1, nx = rem & 1;
    gemm_abt_f32in(smem, addk, Wattn + (h * 4 + 4) * 65536, tmp + h * 65536,
                   256, 256, 256, 256, my * 128, nx * 128);
  } else {
    float(*As)[65] = (float(*)[65])smem;
    float(*Bs)[65] = (float(*)[65])(smem + 16 * 65 * 4);
    int e = blockIdx.x;
    int nx = e & 3, my = e >> 2;
    int m0 = my * 64, n0 = nx * 64;
    int t = threadIdx.x;
    int tm = t & 15, tn = t >> 4;
    int lr = t >> 4, lc = t & 15;
    float acc[4][4] = {};
    float qa[4], wb[4];
    #pragma unroll
    for (int i = 0; i < 4; ++i) {
      int r = lr + i * 16;
      qa[i] = q[(m0 + r) * 256 + lc];
      wb[i] = Woff[(n0 + r) * 256 + lc];
    }
    for (int k0 = 0; k0 < 256; k0 += 16) {
      if (k0) __syncthreads();
      #pragma unroll
      for (int i = 0; i < 4; ++i) {
        int r = lr + i * 16;
        As[lc][r] = qa[i];
        Bs[lc][r] = wb[i];
      }
      if (k0 + 16 < 256) {
        #pragma unroll
        for (int i = 0; i < 4; ++i) {
          int r = lr + i * 16;
          qa[i] = q[(m0 + r) * 256 + k0 + 16 + lc];
          wb[i] = Woff[(n0 + r) * 256 + k0 + 16 + lc];
        }
      }
      __syncthreads();
      #pragma unroll
      for (int k = 0; k < 16; ++k) {
        float a[4], b[4];
        #pragma unroll
        for (int i = 0; i < 4; ++i) a[i] = As[k][tm * 4 + i];
        #pragma unroll
        for (int j = 0; j < 4; ++j) b[j] = Bs[k][tn * 4 + j];
        #pragma unroll
        for (int i = 0; i < 4; ++i)
          #pragma unroll
          for (int j = 0; j < 4; ++j) acc[i][j] += a[i] * b[j];
      }
    }
    #pragma unroll
    for (int i = 0; i < 4; ++i) {
      int b = m0 + tm * 4 + i;
      #pragma unroll
      for (int jp = 0; jp < 2; ++jp) {
        int tt = ((n0 + tn * 4) >> 1) + jp;
        int l = (tt >> 2) & 3;
        float off0 = acc[i][jp * 2]     + boff[2 * tt];
        float off1 = acc[i][jp * 2 + 1] + boff[2 * tt + 1];
        int Hi = shapes[2 * l], Wi = shapes[2 * l + 1];
        float Hf = (float)Hi, Wf = (float)Wi;
        float r0 = refpts[b * 8 + 2 * l], r1 = refpts[b * 8 + 2 * l + 1];
        float l0 = fminf(fmaxf(r0 + off0 / Wf, 0.f), 0.999f);
        float l1 = fminf(fmaxf(r1 + off1 / Hf, 0.f), 0.999f);
        int i0 = (int)(l0 * Hf);
        int i1 = (int)(l1 * Wf);
        fidx[b * 128 + tt] = i0 + i1 * Hi + lvlst[l];
      }
    }
  }
}

// ---------------------------------------------------------------------------
// MFMA level-attention body — R12: As (Q-tile) LDS staging DELETED. The MFMA
// A-fragment is loaded DIRECTLY from qbf (bit-identical bytes: lane (l15,
// quad), tile mi reads 16B at qbf[(mi*256+l15*16+qcol)*256 + jt*64 + ks*32
// + quad*8]). LDS 36864 -> 18432 B (Bs dbuf + fis), doubling blocks/CU —
// R11 counters showed Occupancy 18.6% was the limiter (563 GB/s effective
// gather BW). Gather (Bs) register prefetch pipeline unchanged.
// LDS: Bs0 [0,8704) Bs1 [8704,17408) fis [17408,18432).
// Nlds (64x68 f32 = 17408 B) overlays Bs0+Bs1.
// ---------------------------------------------------------------------------
__device__ __forceinline__ void attn_mfma_body(
    char* smemc,
    const ushort_t* __restrict__ qbf, const ushort_t* __restrict__ xbf,
    const ushort_t* __restrict__ Wlvl, const int* __restrict__ fidx,
    float* __restrict__ attnP, int bx)
{
  unsigned* Bs0 = (unsigned*)smemc;
  unsigned* Bs1 = (unsigned*)(smemc + 8704);
  int* fis = (int*)(smemc + 17408);
  float* Nlds = (float*)smemc;                   // overlay, stride 68

  int h = bx >> 8, l = (bx >> 6) & 3, g = bx & 63;
  int ch = g & 3, g2 = g >> 2;
  int p = g2 >> 2, tg = g2 & 3;
  int c0 = ch * 64;
  int t = threadIdx.x;
  int lane = t & 63, w = t >> 6;
  int quad = lane >> 4, l15 = lane & 15;
  int qcol = p * 4 + tg;
  fis[t] = fidx[(tg * 256 + t) * 128 + h * 16 + l * 4 + p];
  __syncthreads();
  f4 acc[4];
  #pragma unroll
  for (int mi = 0; mi < 4; ++mi) acc[mi] = (f4)0.f;

  int cl = t & 63, sg = t >> 6;
  // direct A-fragment base: row = mi*256 + l15*16 + qcol
  const ushort_t* qb = qbf + (l15 * 16 + qcol) * 256 + quad * 8;

  unsigned vv[16];
  #pragma unroll
  for (int rr = 0; rr < 16; ++rr)
    vv[rr] = xbf[fis[sg * 16 + rr] * 256 + c0 + cl];
  #pragma unroll
  for (int i = 0; i < 4; ++i) {
    uint2 w2; w2.x = vv[i * 4] | (vv[i * 4 + 1] << 16);
    w2.y = vv[i * 4 + 2] | (vv[i * 4 + 3] << 16);
    *(uint2*)&Bs0[cl * 34 + sg * 8 + i * 2] = w2;
  }
  #pragma unroll
  for (int rr = 0; rr < 16; ++rr)
    vv[rr] = xbf[fis[64 + sg * 16 + rr] * 256 + c0 + cl];
  __syncthreads();                               // buf0 visible

  #pragma unroll
  for (int jt = 0; jt < 4; ++jt) {
    unsigned* Bc = (jt & 1) ? Bs1 : Bs0;
    if (jt < 3) {
      unsigned* Bn = (jt & 1) ? Bs0 : Bs1;
      #pragma unroll
      for (int i = 0; i < 4; ++i) {
        uint2 w2; w2.x = vv[i * 4] | (vv[i * 4 + 1] << 16);
        w2.y = vv[i * 4 + 2] | (vv[i * 4 + 3] << 16);
        *(uint2*)&Bn[cl * 34 + sg * 8 + i * 2] = w2;
      }
      if (jt < 2) {
        #pragma unroll
        for (int rr = 0; rr < 16; ++rr)
          vv[rr] = xbf[fis[(jt + 2) * 64 + sg * 16 + rr] * 256 + c0 + cl];
      }
    }
    #pragma unroll
    for (int ks = 0; ks < 2; ++ks) {
      bh8 af[4], bfv;
      #pragma unroll
      for (int mi = 0; mi < 4; ++mi)
        af[mi] = *(const bh8*)(qb + mi * 65536 + jt * 64 + ks * 32);
      {
        const unsigned* bp = &Bc[(w * 16 + l15) * 34 + ks * 16 + quad * 4];
        uint2 b0 = *(const uint2*)bp;
        uint2 b1 = *(const uint2*)(bp + 2);
        u4 bb; bb.x = b0.x; bb.y = b0.y; bb.z = b1.x; bb.w = b1.y;
        bfv = __builtin_bit_cast(bh8, bb);
      }
      #pragma unroll
      for (int mi = 0; mi < 4; ++mi)
        acc[mi] = __builtin_amdgcn_mfma_f32_16x16x32_bf16(af[mi], bfv, acc[mi], 0, 0, 0);
    }
    if (jt < 3) __syncthreads();
  }
  __syncthreads();
  #pragma unroll
  for (int mi = 0; mi < 4; ++mi)
    *(f4*)&Nlds[(w * 16 + l15) * 68 + mi * 16 + quad * 4] = acc[mi];
  __syncthreads();
  {
    int a = t >> 6, u = t & 63;
    const ushort_t* Wr = Wlvl + (h * 4 + l) * 65536 + (a * 64 + u) * 256 + c0;
    float s = 0.f;
    #pragma unroll
    for (int cc = 0; cc < 8; ++cc) {
      u4 wv = *(const u4*)(Wr + cc * 8);
      int cb = cc * 8;
      s += __uint_as_float(wv.x << 16)         * Nlds[(cb + 0) * 68 + u];
      s += __uint_as_float(wv.x & 0xffff0000u) * Nlds[(cb + 1) * 68 + u];
      s += __uint_as_float(wv.y << 16)         * Nlds[(cb + 2) * 68 + u];
      s += __uint_as_float(wv.y & 0xffff0000u) * Nlds[(cb + 3) * 68 + u];
      s += __uint_as_float(wv.z << 16)         * Nlds[(cb + 4) * 68 + u];
      s += __uint_as_float(wv.z & 0xffff0000u) * Nlds[(cb + 5) * 68 + u];
      s += __uint_as_float(wv.w << 16)         * Nlds[(cb + 6) * 68 + u];
      s += __uint_as_float(wv.w & 0xffff0000u) * Nlds[(cb + 7) * 68 + u];
    }
    attnP[ch * 131072 + (h * 16 + l * 4 + a) * 1024 + u * 16 + qcol] = s;
  }
}

// ---------------------------------------------------------------------------
// FUSED C — R12: LDS 18432 B (gemm5 branch needs 15360, fits).
// ---------------------------------------------------------------------------
__global__ __launch_bounds__(256) void k_fused_attn(
    const ushort_t* __restrict__ qbf, const ushort_t* __restrict__ xbf,
    const ushort_t* __restrict__ Wlvl, const int* __restrict__ fidx,
    float* __restrict__ attnP,
    const ushort_t* __restrict__ tmp, float* __restrict__ attn)
{
  __shared__ __align__(16) char smem[18432];
  int bx = blockIdx.x;
  if (bx >= 256) {
    attn_mfma_body(smem, qbf, xbf, Wlvl, fidx, attnP, bx - 256);
  } else {
    int e = bx;                                // 256 blocks: (16,2,8) flattened
    int h = e >> 5, rem = e & 31, my = rem >> 4, nx = rem & 15;
    gemm_abt_12864(smem, tmp + h * 65536, qbf, attn + h * 278528 + 16384,
                   256, 256, 1024, 256, my * 128, nx * 64);
  }
}

// ---------------------------------------------------------------------------
// softmax (R9 form, frozen): 512 threads, 32 row-groups x 9 rows.
// ---------------------------------------------------------------------------
__global__ __launch_bounds__(512) void k_softmax(
    float* __restrict__ attn, const float* __restrict__ attnP,
    ushort_t* __restrict__ attn2bf, float* __restrict__ s1, float* __restrict__ s2)
{
  __shared__ float red[32][17];
  int h = blockIdx.y;
  int bl = threadIdx.x & 15;
  int b = blockIdx.x * 16 + bl;
  int rg = threadIdx.x >> 4;                   // 0..31
  const int R0 = rg * 9;
  float* col = attn + h * 278528 + b;
  float v[9];
  float m = -1e30f;
  #pragma unroll
  for (int i = 0; i < 9; ++i) {
    int r = R0 + i;
    float x;
    if (r < 16) {
      int idx = (h * 16 + r) * 1024 + b;
      x = attnP[idx] + attnP[131072 + idx] + attnP[262144 + idx] + attnP[393216 + idx];
    } else if (r < 272) {
      x = col[r * 1024];
    } else {
      x = -1e30f;
    }
    v[i] = x;
    m = fmaxf(m, x);
  }
  red[rg][bl] = m;
  __syncthreads();
  #pragma unroll
  for (int j = 0; j < 32; ++j) m = fmaxf(m, red[j][bl]);
  float sum = 0.f;
  #pragma unroll
  for (int i = 0; i < 9; ++i) { v[i] = expf(v[i] - m); sum += v[i]; }
  __syncthreads();
  red[rg][bl] = sum;
  __syncthreads();
  float tot = 0.f;
  #pragma unroll
  for (int j = 0; j < 32; ++j) tot += red[j][bl];
  float inv = 1.f / tot;
  #pragma unroll
  for (int i = 0; i < 9; ++i) {
    int r = R0 + i;
    float x = v[i] * inv;
    if (r < 16) col[r * 1024] = x;
    else if (r < 272) attn2bf[h * 262144 + (r - 16) * 1024 + b] = f2bf(x);
  }
  __syncthreads();
  if (rg < 2) {
    float sa = 0.f;
    #pragma unroll
    for (int i = 0; i < 9; ++i) {
      int r = R0 + i;
      if (r < 16) sa += v[i];
    }
    red[rg][bl] = sa;
  }
  __syncthreads();
  if (rg == 0) {
    float sn = (red[0][bl] + red[1][bl]) * inv;
    s1[h * 1024 + b] = sn;
    s2[h * 1024 + b] = 1.f - sn;
  }
}

// ---------------------------------------------------------------------------
// FUSED D (R8 form, frozen): TN 128x64 (0..255) + kbar gather (256..1279).
// ---------------------------------------------------------------------------
__global__ __launch_bounds__(256) void k_fused_kbar_tn(
    const ushort_t* __restrict__ xbf, const float* __restrict__ attn,
    const int* __restrict__ fidx, const ushort_t* __restrict__ attn2,
    const ushort_t* __restrict__ addk, ushort_t* __restrict__ kabar)
{
  __shared__ __align__(16) unsigned Asu[128 * 20];
  __shared__ __align__(16) unsigned Bsu[64 * 20];
  if (blockIdx.x >= 256) {
    int bb = blockIdx.x - 256;
    int h = bb >> 7, b0 = (bb & 127) * 8;
    int t = threadIdx.x;
    int qi = t >> 5, oct = t & 31;
    int b = b0 + qi;
    float aw[16]; int rowv[16];
    #pragma unroll
    for (int r = 0; r < 16; ++r) {
      aw[r]   = attn[(h * 272 + r) * 1024 + b];
      rowv[r] = fidx[b * 128 + h * 16 + r];
    }
    float sacc[8] = {};
    u4 va[8];
    #pragma unroll
    for (int r = 0; r < 8; ++r) va[r] = *(const u4*)(xbf + rowv[r] * 256 + oct * 8);
    #pragma unroll
    for (int r = 0; r < 8; ++r) {
      u4 v = va[r]; float w = aw[r];
      sacc[0] += w * __uint_as_float(v.x << 16);
      sacc[1] += w * __uint_as_float(v.x & 0xffff0000u);
      sacc[2] += w * __uint_as_float(v.y << 16);
      sacc[3] += w * __uint_as_float(v.y & 0xffff0000u);
      sacc[4] += w * __uint_as_float(v.z << 16);
      sacc[5] += w * __uint_as_float(v.z & 0xffff0000u);
      sacc[6] += w * __uint_as_float(v.w << 16);
      sacc[7] += w * __uint_as_float(v.w & 0xffff0000u);
    }
    #pragma unroll
    for (int r = 0; r < 8; ++r) va[r] = *(const u4*)(xbf + rowv[8 + r] * 256 + oct * 8);
    #pragma unroll
    for (int r = 0; r < 8; ++r) {
      u4 v = va[r]; float w = aw[8 + r];
      sacc[0] += w * __uint_as_float(v.x << 16);
      sacc[1] += w * __uint_as_float(v.x & 0xffff0000u);
      sacc[2] += w * __uint_as_float(v.y << 16);
      sacc[3] += w * __uint_as_float(v.y & 0xffff0000u);
      sacc[4] += w * __uint_as_float(v.z << 16);
      sacc[5] += w * __uint_as_float(v.z & 0xffff0000u);
      sacc[6] += w * __uint_as_float(v.w << 16);
      sacc[7] += w * __uint_as_float(v.w & 0xffff0000u);
    }
    u4 o;
    o.x = (unsigned)f2bf(sacc[0]) | ((unsigned)f2bf(sacc[1]) << 16);
    o.y = (unsigned)f2bf(sacc[2]) | ((unsigned)f2bf(sacc[3]) << 16);
    o.z = (unsigned)f2bf(sacc[4]) | ((unsigned)f2bf(sacc[5]) << 16);
    o.w = (unsigned)f2bf(sacc[6]) | ((unsigned)f2bf(sacc[7]) << 16);
    *(u4*)(kabar + (h * 1024 + b) * 512 + oct * 8) = o;
  } else {
    // TN 128x64: C[h][m0+..][256+n0+..] = sum_k attn2[h][k][m] * addk[k][n]
    int e = blockIdx.x;                        // 256 blocks: (8h, 8my, 4nx)
    int h = e >> 5, rem = e & 31, my = rem >> 2, nx = rem & 3;
    const ushort_t* A = attn2 + h * 262144;    // [k*1024 + m]
    const ushort_t* B = addk;                  // [k*256 + n]
    ushort_t* C = kabar + h * 524288;
    int m0 = my * 128, n0 = nx * 64;
    int t = threadIdx.x;
    int lane = t & 63, w = t >> 6;
    int quad = lane >> 4, l15 = lane & 15;
    int wm = w >> 1, wn = w & 1;
    f4 acc[4][2];
    #pragma unroll
    for (int mi = 0; mi < 4; ++mi)
      #pragma unroll
      for (int ni = 0; ni < 2; ++ni) acc[mi][ni] = (f4)0.f;
    int colA = t & 127, halfA = t >> 7;        // A: 128 rows, kpp halfA*4+i
    int colB = t & 63,  grpB  = t >> 6;        // B: 64 rows,  kpp grpB*2+i
    for (int k0 = 0; k0 < 256; k0 += 32) {
      if (k0) __syncthreads();
      #pragma unroll
      for (int i = 0; i < 4; ++i) {
        int kpp = halfA * 4 + i, kk = k0 + kpp * 4;
        unsigned x0 = A[(kk + 0) * 1024 + m0 + colA], x1 = A[(kk + 1) * 1024 + m0 + colA];
        unsigned x2 = A[(kk + 2) * 1024 + m0 + colA], x3 = A[(kk + 3) * 1024 + m0 + colA];
        uint2 va; va.x = x0 | (x1 << 16); va.y = x2 | (x3 << 16);
        *(uint2*)&Asu[colA * 20 + kpp * 2] = va;
      }
      #pragma unroll
      for (int i = 0; i < 2; ++i) {
        int kpp = grpB * 2 + i, kk = k0 + kpp * 4;
        unsigned y0 = B[(kk + 0) * 256 + n0 + colB], y1 = B[(kk + 1) * 256 + n0 + colB];
        unsigned y2 = B[(kk + 2) * 256 + n0 + colB], y3 = B[(kk + 3) * 256 + n0 + colB];
        uint2 vb; vb.x = y0 | (y1 << 16); vb.y = y2 | (y3 << 16);
        *(uint2*)&Bsu[colB * 20 + kpp * 2] = vb;
      }
      __syncthreads();
      bh8 af[4], bf2[2];
      #pragma unroll
      for (int mi = 0; mi < 4; ++mi)
        af[mi] = *(bh8*)((const ushort_t*)Asu + (wm * 64 + mi * 16 + l15) * 40 + quad * 8);
      #pragma unroll
      for (int ni = 0; ni < 2; ++ni)
        bf2[ni] = *(bh8*)((const ushort_t*)Bsu + (wn * 32 + ni * 16 + l15) * 40 + quad * 8);
      #pragma unroll
      for (int mi = 0; mi < 4; ++mi)
        #pragma unroll
        for (int ni = 0; ni < 2; ++ni)
          acc[mi][ni] = __builtin_amdgcn_mfma_f32_16x16x32_bf16(af[mi], bf2[ni], acc[mi][ni], 0, 0, 0);
    }
    #pragma unroll
    for (int mi = 0; mi < 4; ++mi)
      #pragma unroll
      for (int ni = 0; ni < 2; ++ni)
        #pragma unroll
        for (int r = 0; r < 4; ++r) {
          int mg = m0 + wm * 64 + mi * 16 + quad * 4 + r;
          int ng = n0 + wn * 32 + ni * 16 + l15;
          C[mg * 512 + 256 + ng] = f2bf(acc[mi][ni][r]);
        }
  }
}

// ---------------------------------------------------------------------------
// gemm_val (R9 form, frozen): 128x64 tiles -> 256 blocks.
// ---------------------------------------------------------------------------
__global__ __launch_bounds__(256) void gemm_val_k(
    const ushort_t* __restrict__ kabar, const ushort_t* __restrict__ Wcat,
    float* __restrict__ Y)
{
  __shared__ __align__(16) char smem[20480];
  int h = blockIdx.z;
  gemm_abt_12864(smem, kabar + h * 524288, Wcat + h * 131072, Y + h * 262144,
                 512, 512, 256, 512, blockIdx.y * 128, blockIdx.x * 64);
}

// ------------------------------- final combine ------------------------------
__global__ __launch_bounds__(256) void k_combine(
    const float* __restrict__ q, const float* __restrict__ Wmix,
    const float* __restrict__ Y,
    const float* __restrict__ s1, const float* __restrict__ s2,
    const float* __restrict__ bval, float* __restrict__ out)
{
  int b = blockIdx.x, c = threadIdx.x;
  float w[9];
  float m = -1e30f;
  #pragma unroll
  for (int j = 0; j < 9; ++j) { w[j] = Wmix[c * 9 + j]; m = fmaxf(m, w[j]); }
  float tot = 0.f;
  #pragma unroll
  for (int j = 0; j < 9; ++j) { w[j] = expf(w[j] - m); tot += w[j]; }
  float inv = 1.f / tot;
  float res = q[b * 256 + c] * w[8] * inv;
  #pragma unroll
  for (int hh = 0; hh < 8; ++hh) {
    float y = Y[(hh * 1024 + b) * 256 + c]
            + s1[hh * 1024 + b] * bval[(2 * hh) * 256 + c]
            + s2[hh * 1024 + b] * bval[(2 * hh + 1) * 256 + c];
    res += w[hh] * inv * y;
  }
  out[b * 256 + c] = res;
}

extern "C" void kernel_launch(void* const* d_in, const int* in_sizes, int n_in,
                              void* d_out, int out_size, void* d_ws, size_t ws_size,
                              hipStream_t stream) {
  (void)in_sizes; (void)n_in; (void)out_size; (void)ws_size;
  const float* q      = (const float*)d_in[0];
  const float* refpts = (const float*)d_in[1];
  const float* xin    = (const float*)d_in[2];
  const int*   shapes = (const int*)d_in[3];
  const float* addk   = (const float*)d_in[4];
  const int*   lvlst  = (const int*)d_in[5];
  const float* Woff   = (const float*)d_in[6];
  const float* boff   = (const float*)d_in[7];
  const float* Wattn  = (const float*)d_in[8];
  const float* Wval   = (const float*)d_in[9];
  const float* bval   = (const float*)d_in[10];
  const float* Wmix   = (const float*)d_in[11];
  float* out = (float*)d_out;
  float* ws  = (float*)d_ws;

  int*   fidx    = (int*)ws;                  // [0, 131072)
  float* s1      = ws + 393216;               // 8192
  float* s2      = ws + 401408;               // 8192
  float* attn    = ws + 409600;               // 8*272*1024 fp32 (dead after fused_d)
  float* Y       = ws + 409600;               // overlays attn (written by gemm_val_k)
  ushort_t* arena = (ushort_t*)(ws + 2637824);
  ushort_t* q_bf     = arena;                 // 262144
  ushort_t* xin_bf   = arena + 262144;        // 3403264
  ushort_t* addk_bf  = arena + 3665408;       // 65536
  ushort_t* Wcat_bf  = arena + 3730944;       // 1048576 (stride 131072/head)
  ushort_t* Wlvl_bf  = arena + 6352384;       // 2097152
  ushort_t* tmp_bf   = arena + 8449536;       // 524288
  ushort_t* attn2_bf = arena + 8973824;       // 2097152
  ushort_t* kabar_bf = arena + 11070976;      // 4194304 (8*1024*512)
  float* attnP = (float*)(arena + 15265280);  // 4 * 131072 f (per-ch partials)

  k_fused_cast_off<<<2048, 256, 0, stream>>>(q, xin, addk, Wval, Wattn, arena,
                                             Woff, boff, refpts, shapes, lvlst,
                                             fidx, tmp_bf);
  k_fused_attn<<<2304, 256, 0, stream>>>(q_bf, xin_bf, Wlvl_bf, fidx, attnP,
                                         tmp_bf, attn);
  k_softmax<<<dim3(64, 8), 512, 0, stream>>>(attn, attnP, attn2_bf, s1, s2);
  k_fused_kbar_tn<<<1280, 256, 0, stream>>>(xin_bf, attn, fidx, attn2_bf,
                                            addk_bf, kabar_bf);
  gemm_val_k<<<dim3(4, 8, 8), 256, 0, stream>>>(kabar_bf, Wcat_bf, Y);
  k_combine<<<1024, 256, 0, stream>>>(q, Wmix, Y, s1, s2, bval, out);
}

// Round 14
// 165.550 us; speedup vs baseline: 1.1866x; 1.1257x over previous
//
#include <hip/hip_runtime.h>

typedef unsigned short ushort_t;
typedef __attribute__((ext_vector_type(8))) short bh8;     // 8 bf16 (4 VGPRs)
typedef __attribute__((ext_vector_type(4))) float f4;      // 4 fp32 acc
typedef __attribute__((ext_vector_type(4))) unsigned int u4;

__device__ __forceinline__ ushort_t f2bf(float f) {
  unsigned u = __float_as_uint(f);
  return (ushort_t)((u + 0x7FFFu + ((u >> 16) & 1u)) >> 16);
}
__device__ __forceinline__ float bf2f(ushort_t v) {
  return __uint_as_float(((unsigned)v) << 16);
}

// ---------------------------------------------------------------------------
// bf16 MFMA GEMM core, abt form, LDS passed in (20480 B: As 10240 + Bs 10240)
// Register double-buffered staging (R1).
// ---------------------------------------------------------------------------
template <typename OutT>
__device__ __forceinline__ void gemm_abt_core(
    char* smem,
    const ushort_t* __restrict__ A, const ushort_t* __restrict__ B,
    OutT* __restrict__ C, int ldA, int ldB, int ldC, int K, int m0, int n0)
{
  ushort_t* As = (ushort_t*)smem;
  ushort_t* Bs = (ushort_t*)(smem + 10240);
  int t = threadIdx.x;
  int lane = t & 63, w = t >> 6;
  int quad = lane >> 4, l15 = lane & 15;
  int wm = w >> 1, wn = w & 1;
  f4 acc[4][4];
  #pragma unroll
  for (int mi = 0; mi < 4; ++mi)
    #pragma unroll
    for (int ni = 0; ni < 4; ++ni) acc[mi][ni] = (f4)0.f;
  int row = t >> 1, kh = (t & 1) * 16;
  const ushort_t* pa = A + (m0 + row) * ldA + kh;
  const ushort_t* pb = B + (n0 + row) * ldB + kh;
  u4 va0 = *(const u4*)(pa);     u4 va1 = *(const u4*)(pa + 8);
  u4 vb0 = *(const u4*)(pb);     u4 vb1 = *(const u4*)(pb + 8);
  for (int k0 = 0; k0 < K; k0 += 32) {
    if (k0) __syncthreads();
    {
      u4* da = (u4*)(As + row * 40 + kh); da[0] = va0; da[1] = va1;
      u4* db = (u4*)(Bs + row * 40 + kh); db[0] = vb0; db[1] = vb1;
    }
    if (k0 + 32 < K) {
      va0 = *(const u4*)(pa + k0 + 32); va1 = *(const u4*)(pa + k0 + 40);
      vb0 = *(const u4*)(pb + k0 + 32); vb1 = *(const u4*)(pb + k0 + 40);
    }
    __syncthreads();
    bh8 af[4], bfv[4];
    #pragma unroll
    for (int mi = 0; mi < 4; ++mi)
      af[mi] = *(bh8*)(As + (wm * 64 + mi * 16 + l15) * 40 + quad * 8);
    #pragma unroll
    for (int ni = 0; ni < 4; ++ni)
      bfv[ni] = *(bh8*)(Bs + (wn * 64 + ni * 16 + l15) * 40 + quad * 8);
    #pragma unroll
    for (int mi = 0; mi < 4; ++mi)
      #pragma unroll
      for (int ni = 0; ni < 4; ++ni)
        acc[mi][ni] = __builtin_amdgcn_mfma_f32_16x16x32_bf16(af[mi], bfv[ni], acc[mi][ni], 0, 0, 0);
  }
  #pragma unroll
  for (int mi = 0; mi < 4; ++mi)
    #pragma unroll
    for (int ni = 0; ni < 4; ++ni)
      #pragma unroll
      for (int r = 0; r < 4; ++r) {
        int mg = m0 + wm * 64 + mi * 16 + quad * 4 + r;
        int ng = n0 + wn * 64 + ni * 16 + l15;
        if constexpr (sizeof(OutT) == 4) C[mg * ldC + ng] = acc[mi][ni][r];
        else C[mg * ldC + ng] = (OutT)f2bf(acc[mi][ni][r]);
      }
}

// ---------------------------------------------------------------------------
// 128x64-tile variant (R5; R9: also used by gemm_val_k). LDS 15360 B.
// ---------------------------------------------------------------------------
__device__ __forceinline__ void gemm_abt_12864(
    char* smem,
    const ushort_t* __restrict__ A, const ushort_t* __restrict__ B,
    float* __restrict__ C, int ldA, int ldB, int ldC, int K, int m0, int n0)
{
  ushort_t* As = (ushort_t*)smem;
  ushort_t* Bs = (ushort_t*)(smem + 10240);
  int t = threadIdx.x;
  int lane = t & 63, w = t >> 6;
  int quad = lane >> 4, l15 = lane & 15;
  int wm = w >> 1, wn = w & 1;
  f4 acc[4][2];
  #pragma unroll
  for (int mi = 0; mi < 4; ++mi)
    #pragma unroll
    for (int ni = 0; ni < 2; ++ni) acc[mi][ni] = (f4)0.f;
  int rowA = t >> 1, khA = (t & 1) * 16;
  int rowB = t >> 2, khB = (t & 3) * 8;
  const ushort_t* pa = A + (m0 + rowA) * ldA + khA;
  const ushort_t* pb = B + (n0 + rowB) * ldB + khB;
  u4 va0 = *(const u4*)(pa); u4 va1 = *(const u4*)(pa + 8);
  u4 vb0 = *(const u4*)(pb);
  for (int k0 = 0; k0 < K; k0 += 32) {
    if (k0) __syncthreads();
    {
      u4* da = (u4*)(As + rowA * 40 + khA); da[0] = va0; da[1] = va1;
      u4* db = (u4*)(Bs + rowB * 40 + khB); db[0] = vb0;
    }
    if (k0 + 32 < K) {
      va0 = *(const u4*)(pa + k0 + 32); va1 = *(const u4*)(pa + k0 + 40);
      vb0 = *(const u4*)(pb + k0 + 32);
    }
    __syncthreads();
    bh8 af[4], bf2[2];
    #pragma unroll
    for (int mi = 0; mi < 4; ++mi)
      af[mi] = *(bh8*)(As + (wm * 64 + mi * 16 + l15) * 40 + quad * 8);
    #pragma unroll
    for (int ni = 0; ni < 2; ++ni)
      bf2[ni] = *(bh8*)(Bs + (wn * 32 + ni * 16 + l15) * 40 + quad * 8);
    #pragma unroll
    for (int mi = 0; mi < 4; ++mi)
      #pragma unroll
      for (int ni = 0; ni < 2; ++ni)
        acc[mi][ni] = __builtin_amdgcn_mfma_f32_16x16x32_bf16(af[mi], bf2[ni], acc[mi][ni], 0, 0, 0);
  }
  #pragma unroll
  for (int mi = 0; mi < 4; ++mi)
    #pragma unroll
    for (int ni = 0; ni < 2; ++ni)
      #pragma unroll
      for (int r = 0; r < 4; ++r) {
        int mg = m0 + wm * 64 + mi * 16 + quad * 4 + r;
        int ng = n0 + wn * 32 + ni * 16 + l15;
        C[mg * ldC + ng] = acc[mi][ni][r];
      }
}

// ---------------------------------------------------------------------------
// fp32-input variant (R7 form: no register prefetch).
// ---------------------------------------------------------------------------
__device__ __forceinline__ void gemm_abt_f32in(
    char* smem,
    const float* __restrict__ A, const float* __restrict__ B,
    ushort_t* __restrict__ C, int ldA, int ldB, int ldC, int K, int m0, int n0)
{
  ushort_t* As = (ushort_t*)smem;
  ushort_t* Bs = (ushort_t*)(smem + 10240);
  int t = threadIdx.x;
  int lane = t & 63, w = t >> 6;
  int quad = lane >> 4, l15 = lane & 15;
  int wm = w >> 1, wn = w & 1;
  f4 acc[4][4];
  #pragma unroll
  for (int mi = 0; mi < 4; ++mi)
    #pragma unroll
    for (int ni = 0; ni < 4; ++ni) acc[mi][ni] = (f4)0.f;
  int row = t >> 1, kh = (t & 1) * 16;
  const float* pa = A + (m0 + row) * ldA + kh;
  const float* pb = B + (n0 + row) * ldB + kh;
  for (int k0 = 0; k0 < K; k0 += 32) {
    if (k0) __syncthreads();
    {
      ushort_t* da = As + row * 40 + kh;
      ushort_t* db = Bs + row * 40 + kh;
      #pragma unroll
      for (int i = 0; i < 4; ++i) {
        float4 fa = *(const float4*)(pa + k0 + i * 4);
        float4 fb = *(const float4*)(pb + k0 + i * 4);
        ushort4 oa; oa.x = f2bf(fa.x); oa.y = f2bf(fa.y);
        oa.z = f2bf(fa.z); oa.w = f2bf(fa.w);
        *(ushort4*)(da + i * 4) = oa;
        ushort4 ob; ob.x = f2bf(fb.x); ob.y = f2bf(fb.y);
        ob.z = f2bf(fb.z); ob.w = f2bf(fb.w);
        *(ushort4*)(db + i * 4) = ob;
      }
    }
    __syncthreads();
    bh8 af[4], bfv[4];
    #pragma unroll
    for (int mi = 0; mi < 4; ++mi)
      af[mi] = *(bh8*)(As + (wm * 64 + mi * 16 + l15) * 40 + quad * 8);
    #pragma unroll
    for (int ni = 0; ni < 4; ++ni)
      bfv[ni] = *(bh8*)(Bs + (wn * 64 + ni * 16 + l15) * 40 + quad * 8);
    #pragma unroll
    for (int mi = 0; mi < 4; ++mi)
      #pragma unroll
      for (int ni = 0; ni < 4; ++ni)
        acc[mi][ni] = __builtin_amdgcn_mfma_f32_16x16x32_bf16(af[mi], bfv[ni], acc[mi][ni], 0, 0, 0);
  }
  #pragma unroll
  for (int mi = 0; mi < 4; ++mi)
    #pragma unroll
    for (int ni = 0; ni < 4; ++ni)
      #pragma unroll
      for (int r = 0; r < 4; ++r) {
        int mg = m0 + wm * 64 + mi * 16 + quad * 4 + r;
        int ng = n0 + wn * 64 + ni * 16 + l15;
        C[mg * ldC + ng] = (ushort_t)f2bf(acc[mi][ni][r]);
      }
}

// cast section address computation (shared by the x2-unrolled loop)
__device__ __forceinline__ const float* cast_src(
    int i, const float* __restrict__ q, const float* __restrict__ xin,
    const float* __restrict__ addk, const float* __restrict__ Wval,
    const float* __restrict__ Wattn, ushort_t* __restrict__ arena,
    ushort_t** dst)
{
  const float* src; int e;
  if (i < 65536)        { src = q    + i * 4;            *dst = arena + i * 4; }
  else if (i < 916352)  { e = i - 65536;  src = xin  + e * 4; *dst = arena + 262144  + e * 4; }
  else if (i < 932736)  { e = i - 916352; src = addk + e * 4; *dst = arena + 3665408 + e * 4; }
  else if (i < 1194880) {                     // Wcat: [Wv1 row | Wv2 row]
    e = i - 932736; int el = e * 4;           // el in [0, 1048576)
    int h = el >> 17, r = el & 131071;
    int c = r >> 9, k = r & 511;
    src = Wval + (2 * h + (k >> 8)) * 65536 + c * 256 + (k & 255);
    *dst = arena + 3730944 + el;
  }
  else {                                      // Wattn level mats 0..31
    e = i - 1194880;
    src = Wattn + e * 4;
    *dst = arena + 6352384 + e * 4;
  }
  return src;
}

// ---------------------------------------------------------------------------
// FUSED A (R10 form, frozen).
// ---------------------------------------------------------------------------
__global__ __launch_bounds__(256) void k_fused_cast_off(
    const float* __restrict__ q, const float* __restrict__ xin,
    const float* __restrict__ addk, const float* __restrict__ Wval,
    const float* __restrict__ Wattn, ushort_t* __restrict__ arena,
    const float* __restrict__ Woff, const float* __restrict__ boff,
    const float* __restrict__ refpts, const int* __restrict__ shapes,
    const int* __restrict__ lvlst, int* __restrict__ fidx,
    ushort_t* __restrict__ tmp)
{
  __shared__ __align__(16) char smem[20480];
  if (blockIdx.x >= 96) {
    const int total4 = 1719168;
    const int S = 1952 * 256;
    for (int i = (blockIdx.x - 96) * 256 + threadIdx.x; i < total4; i += 2 * S) {
      ushort_t* d1; const float* s1 = cast_src(i, q, xin, addk, Wval, Wattn, arena, &d1);
      float4 v1 = *(const float4*)s1;
      int i2 = i + S;
      ushort_t* d2 = nullptr; float4 v2 = v1;
      if (i2 < total4) {
        const float* s2 = cast_src(i2, q, xin, addk, Wval, Wattn, arena, &d2);
        v2 = *(const float4*)s2;
      }
      ushort4 o1; o1.x = f2bf(v1.x); o1.y = f2bf(v1.y); o1.z = f2bf(v1.z); o1.w = f2bf(v1.w);
      *(ushort4*)d1 = o1;
      if (i2 < total4) {
        ushort4 o2; o2.x = f2bf(v2.x); o2.y = f2bf(v2.y); o2.z = f2bf(v2.z); o2.w = f2bf(v2.w);
        *(ushort4*)d2 = o2;
      }
    }
  } else if (blockIdx.x >= 64) {
    int e = blockIdx.x - 64;                   // 32 blocks: (2,2,8) flattened
    int h = e >> 2, rem = e & 3, my = rem >> 1, nx = rem & 1;
    gemm_abt_f32in(smem, addk, Wattn + (h * 4 + 4) * 65536, tmp + h * 65536,
                   256, 256, 256, 256, my * 128, nx * 128);
  } else {
    float(*As)[65] = (float(*)[65])smem;
    float(*Bs)[65] = (float(*)[65])(smem + 16 * 65 * 4);
    int e = blockIdx.x;
    int nx = e & 3, my = e >> 2;
    int m0 = my * 64, n0 = nx * 64;
    int t = threadIdx.x;
    int tm = t & 15, tn = t >> 4;
    int lr = t >> 4, lc = t & 15;
    float acc[4][4] = {};
    float qa[4], wb[4];
    #pragma unroll
    for (int i = 0; i < 4; ++i) {
      int r = lr + i * 16;
      qa[i] = q[(m0 + r) * 256 + lc];
      wb[i] = Woff[(n0 + r) * 256 + lc];
    }
    for (int k0 = 0; k0 < 256; k0 += 16) {
      if (k0) __syncthreads();
      #pragma unroll
      for (int i = 0; i < 4; ++i) {
        int r = lr + i * 16;
        As[lc][r] = qa[i];
        Bs[lc][r] = wb[i];
      }
      if (k0 + 16 < 256) {
        #pragma unroll
        for (int i = 0; i < 4; ++i) {
          int r = lr + i * 16;
          qa[i] = q[(m0 + r) * 256 + k0 + 16 + lc];
          wb[i] = Woff[(n0 + r) * 256 + k0 + 16 + lc];
        }
      }
      __syncthreads();
      #pragma unroll
      for (int k = 0; k < 16; ++k) {
        float a[4], b[4];
        #pragma unroll
        for (int i = 0; i < 4; ++i) a[i] = As[k][tm * 4 + i];
        #pragma unroll
        for (int j = 0; j < 4; ++j) b[j] = Bs[k][tn * 4 + j];
        #pragma unroll
        for (int i = 0; i < 4; ++i)
          #pragma unroll
          for (int j = 0; j < 4; ++j) acc[i][j] += a[i] * b[j];
      }
    }
    #pragma unroll
    for (int i = 0; i < 4; ++i) {
      int b = m0 + tm * 4 + i;
      #pragma unroll
      for (int jp = 0; jp < 2; ++jp) {
        int tt = ((n0 + tn * 4) >> 1) + jp;
        int l = (tt >> 2) & 3;
        float off0 = acc[i][jp * 2]     + boff[2 * tt];
        float off1 = acc[i][jp * 2 + 1] + boff[2 * tt + 1];
        int Hi = shapes[2 * l], Wi = shapes[2 * l + 1];
        float Hf = (float)Hi, Wf = (float)Wi;
        float r0 = refpts[b * 8 + 2 * l], r1 = refpts[b * 8 + 2 * l + 1];
        float l0 = fminf(fmaxf(r0 + off0 / Wf, 0.f), 0.999f);
        float l1 = fminf(fmaxf(r1 + off1 / Hf, 0.f), 0.999f);
        int i0 = (int)(l0 * Hf);
        int i1 = (int)(l1 * Wf);
        fidx[b * 128 + tt] = i0 + i1 * Hi + lvlst[l];
      }
    }
  }
}

// ---------------------------------------------------------------------------
// MFMA level-attention body — R13: exact revert to the R5/R10 form (As+Bs
// double-buffered in LDS, register gather prefetch, LDS 36864). R12's
// As-deletion raised occupancy (18.6->26.5%) but put the A-fragment loads
// on the global critical path (VGPR 68, no hoisting) -> C 30->49.5us.
// LDS staging is load-bearing latency hiding here; keep it.
// ---------------------------------------------------------------------------
__device__ __forceinline__ void attn_mfma_body(
    char* smemc,
    const ushort_t* __restrict__ qbf, const ushort_t* __restrict__ xbf,
    const ushort_t* __restrict__ Wlvl, const int* __restrict__ fidx,
    float* __restrict__ attnP, int bx)
{
  unsigned* Bs0 = (unsigned*)smemc;
  unsigned* Bs1 = (unsigned*)(smemc + 8704);
  ushort_t* As0 = (ushort_t*)(smemc + 17408);
  ushort_t* As1 = (ushort_t*)(smemc + 26624);
  int* fis = (int*)(smemc + 35840);
  float* Nlds = (float*)smemc;                   // overlay, stride 68

  int h = bx >> 8, l = (bx >> 6) & 3, g = bx & 63;
  int ch = g & 3, g2 = g >> 2;
  int p = g2 >> 2, tg = g2 & 3;
  int c0 = ch * 64;
  int t = threadIdx.x;
  int lane = t & 63, w = t >> 6;
  int quad = lane >> 4, l15 = lane & 15;
  int qcol = p * 4 + tg;
  fis[t] = fidx[(tg * 256 + t) * 128 + h * 16 + l * 4 + p];
  __syncthreads();
  f4 acc[4];
  #pragma unroll
  for (int mi = 0; mi < 4; ++mi) acc[mi] = (f4)0.f;

  int cl = t & 63, sg = t >> 6;
  int uu = t >> 2, jj0 = (t & 3) * 16;
  const ushort_t* qrow = qbf + (uu * 16 + qcol) * 256 + jj0;

  unsigned vv[16];
  u4 a0, a1;
  #pragma unroll
  for (int rr = 0; rr < 16; ++rr)
    vv[rr] = xbf[fis[sg * 16 + rr] * 256 + c0 + cl];
  { const u4* src = (const u4*)qrow; a0 = src[0]; a1 = src[1]; }
  #pragma unroll
  for (int i = 0; i < 4; ++i) {
    uint2 w2; w2.x = vv[i * 4] | (vv[i * 4 + 1] << 16);
    w2.y = vv[i * 4 + 2] | (vv[i * 4 + 3] << 16);
    *(uint2*)&Bs0[cl * 34 + sg * 8 + i * 2] = w2;
  }
  { u4* dst = (u4*)(As0 + uu * 72 + jj0); dst[0] = a0; dst[1] = a1; }
  #pragma unroll
  for (int rr = 0; rr < 16; ++rr)
    vv[rr] = xbf[fis[64 + sg * 16 + rr] * 256 + c0 + cl];
  { const u4* src = (const u4*)(qrow + 64); a0 = src[0]; a1 = src[1]; }
  __syncthreads();                               // buf0 visible

  #pragma unroll
  for (int jt = 0; jt < 4; ++jt) {
    unsigned* Bc = (jt & 1) ? Bs1 : Bs0;
    ushort_t* Ac = (jt & 1) ? As1 : As0;
    if (jt < 3) {
      unsigned* Bn = (jt & 1) ? Bs0 : Bs1;
      ushort_t* An = (jt & 1) ? As0 : As1;
      #pragma unroll
      for (int i = 0; i < 4; ++i) {
        uint2 w2; w2.x = vv[i * 4] | (vv[i * 4 + 1] << 16);
        w2.y = vv[i * 4 + 2] | (vv[i * 4 + 3] << 16);
        *(uint2*)&Bn[cl * 34 + sg * 8 + i * 2] = w2;
      }
      { u4* dst = (u4*)(An + uu * 72 + jj0); dst[0] = a0; dst[1] = a1; }
      if (jt < 2) {
        #pragma unroll
        for (int rr = 0; rr < 16; ++rr)
          vv[rr] = xbf[fis[(jt + 2) * 64 + sg * 16 + rr] * 256 + c0 + cl];
        const u4* src = (const u4*)(qrow + (jt + 2) * 64);
        a0 = src[0]; a1 = src[1];
      }
    }
    #pragma unroll
    for (int ks = 0; ks < 2; ++ks) {
      bh8 af[4], bfv;
      #pragma unroll
      for (int mi = 0; mi < 4; ++mi)
        af[mi] = *(bh8*)(Ac + (mi * 16 + l15) * 72 + ks * 32 + quad * 8);
      {
        const unsigned* bp = &Bc[(w * 16 + l15) * 34 + ks * 16 + quad * 4];
        uint2 b0 = *(const uint2*)bp;
        uint2 b1 = *(const uint2*)(bp + 2);
        u4 bb; bb.x = b0.x; bb.y = b0.y; bb.z = b1.x; bb.w = b1.y;
        bfv = __builtin_bit_cast(bh8, bb);
      }
      #pragma unroll
      for (int mi = 0; mi < 4; ++mi)
        acc[mi] = __builtin_amdgcn_mfma_f32_16x16x32_bf16(af[mi], bfv, acc[mi], 0, 0, 0);
    }
    if (jt < 3) __syncthreads();
  }
  __syncthreads();
  #pragma unroll
  for (int mi = 0; mi < 4; ++mi)
    *(f4*)&Nlds[(w * 16 + l15) * 68 + mi * 16 + quad * 4] = acc[mi];
  __syncthreads();
  {
    int a = t >> 6, u = t & 63;
    const ushort_t* Wr = Wlvl + (h * 4 + l) * 65536 + (a * 64 + u) * 256 + c0;
    float s = 0.f;
    #pragma unroll
    for (int cc = 0; cc < 8; ++cc) {
      u4 wv = *(const u4*)(Wr + cc * 8);
      int cb = cc * 8;
      s += __uint_as_float(wv.x << 16)         * Nlds[(cb + 0) * 68 + u];
      s += __uint_as_float(wv.x & 0xffff0000u) * Nlds[(cb + 1) * 68 + u];
      s += __uint_as_float(wv.y << 16)         * Nlds[(cb + 2) * 68 + u];
      s += __uint_as_float(wv.y & 0xffff0000u) * Nlds[(cb + 3) * 68 + u];
      s += __uint_as_float(wv.z << 16)         * Nlds[(cb + 4) * 68 + u];
      s += __uint_as_float(wv.z & 0xffff0000u) * Nlds[(cb + 5) * 68 + u];
      s += __uint_as_float(wv.w << 16)         * Nlds[(cb + 6) * 68 + u];
      s += __uint_as_float(wv.w & 0xffff0000u) * Nlds[(cb + 7) * 68 + u];
    }
    attnP[ch * 131072 + (h * 16 + l * 4 + a) * 1024 + u * 16 + qcol] = s;
  }
}

// ---------------------------------------------------------------------------
// FUSED C (R10 form, reverted): gemm5 128x64 (0..255) + attn (256..2303).
// ---------------------------------------------------------------------------
__global__ __launch_bounds__(256) void k_fused_attn(
    const ushort_t* __restrict__ qbf, const ushort_t* __restrict__ xbf,
    const ushort_t* __restrict__ Wlvl, const int* __restrict__ fidx,
    float* __restrict__ attnP,
    const ushort_t* __restrict__ tmp, float* __restrict__ attn)
{
  __shared__ __align__(16) char smem[36864];
  int bx = blockIdx.x;
  if (bx >= 256) {
    attn_mfma_body(smem, qbf, xbf, Wlvl, fidx, attnP, bx - 256);
  } else {
    int e = bx;                                // 256 blocks: (16,2,8) flattened
    int h = e >> 5, rem = e & 31, my = rem >> 4, nx = rem & 15;
    gemm_abt_12864(smem, tmp + h * 65536, qbf, attn + h * 278528 + 16384,
                   256, 256, 1024, 256, my * 128, nx * 64);
  }
}

// ---------------------------------------------------------------------------
// softmax (R9 form, frozen): 512 threads, 32 row-groups x 9 rows.
// ---------------------------------------------------------------------------
__global__ __launch_bounds__(512) void k_softmax(
    float* __restrict__ attn, const float* __restrict__ attnP,
    ushort_t* __restrict__ attn2bf, float* __restrict__ s1, float* __restrict__ s2)
{
  __shared__ float red[32][17];
  int h = blockIdx.y;
  int bl = threadIdx.x & 15;
  int b = blockIdx.x * 16 + bl;
  int rg = threadIdx.x >> 4;                   // 0..31
  const int R0 = rg * 9;
  float* col = attn + h * 278528 + b;
  float v[9];
  float m = -1e30f;
  #pragma unroll
  for (int i = 0; i < 9; ++i) {
    int r = R0 + i;
    float x;
    if (r < 16) {
      int idx = (h * 16 + r) * 1024 + b;
      x = attnP[idx] + attnP[131072 + idx] + attnP[262144 + idx] + attnP[393216 + idx];
    } else if (r < 272) {
      x = col[r * 1024];
    } else {
      x = -1e30f;
    }
    v[i] = x;
    m = fmaxf(m, x);
  }
  red[rg][bl] = m;
  __syncthreads();
  #pragma unroll
  for (int j = 0; j < 32; ++j) m = fmaxf(m, red[j][bl]);
  float sum = 0.f;
  #pragma unroll
  for (int i = 0; i < 9; ++i) { v[i] = expf(v[i] - m); sum += v[i]; }
  __syncthreads();
  red[rg][bl] = sum;
  __syncthreads();
  float tot = 0.f;
  #pragma unroll
  for (int j = 0; j < 32; ++j) tot += red[j][bl];
  float inv = 1.f / tot;
  #pragma unroll
  for (int i = 0; i < 9; ++i) {
    int r = R0 + i;
    float x = v[i] * inv;
    if (r < 16) col[r * 1024] = x;
    else if (r < 272) attn2bf[h * 262144 + (r - 16) * 1024 + b] = f2bf(x);
  }
  __syncthreads();
  if (rg < 2) {
    float sa = 0.f;
    #pragma unroll
    for (int i = 0; i < 9; ++i) {
      int r = R0 + i;
      if (r < 16) sa += v[i];
    }
    red[rg][bl] = sa;
  }
  __syncthreads();
  if (rg == 0) {
    float sn = (red[0][bl] + red[1][bl]) * inv;
    s1[h * 1024 + b] = sn;
    s2[h * 1024 + b] = 1.f - sn;
  }
}

// ---------------------------------------------------------------------------
// FUSED D (R8 form, frozen): TN 128x64 (0..255) + kbar gather (256..1279).
// ---------------------------------------------------------------------------
__global__ __launch_bounds__(256) void k_fused_kbar_tn(
    const ushort_t* __restrict__ xbf, const float* __restrict__ attn,
    const int* __restrict__ fidx, const ushort_t* __restrict__ attn2,
    const ushort_t* __restrict__ addk, ushort_t* __restrict__ kabar)
{
  __shared__ __align__(16) unsigned Asu[128 * 20];
  __shared__ __align__(16) unsigned Bsu[64 * 20];
  if (blockIdx.x >= 256) {
    int bb = blockIdx.x - 256;
    int h = bb >> 7, b0 = (bb & 127) * 8;
    int t = threadIdx.x;
    int qi = t >> 5, oct = t & 31;
    int b = b0 + qi;
    float aw[16]; int rowv[16];
    #pragma unroll
    for (int r = 0; r < 16; ++r) {
      aw[r]   = attn[(h * 272 + r) * 1024 + b];
      rowv[r] = fidx[b * 128 + h * 16 + r];
    }
    float sacc[8] = {};
    u4 va[8];
    #pragma unroll
    for (int r = 0; r < 8; ++r) va[r] = *(const u4*)(xbf + rowv[r] * 256 + oct * 8);
    #pragma unroll
    for (int r = 0; r < 8; ++r) {
      u4 v = va[r]; float w = aw[r];
      sacc[0] += w * __uint_as_float(v.x << 16);
      sacc[1] += w * __uint_as_float(v.x & 0xffff0000u);
      sacc[2] += w * __uint_as_float(v.y << 16);
      sacc[3] += w * __uint_as_float(v.y & 0xffff0000u);
      sacc[4] += w * __uint_as_float(v.z << 16);
      sacc[5] += w * __uint_as_float(v.z & 0xffff0000u);
      sacc[6] += w * __uint_as_float(v.w << 16);
      sacc[7] += w * __uint_as_float(v.w & 0xffff0000u);
    }
    #pragma unroll
    for (int r = 0; r < 8; ++r) va[r] = *(const u4*)(xbf + rowv[8 + r] * 256 + oct * 8);
    #pragma unroll
    for (int r = 0; r < 8; ++r) {
      u4 v = va[r]; float w = aw[8 + r];
      sacc[0] += w * __uint_as_float(v.x << 16);
      sacc[1] += w * __uint_as_float(v.x & 0xffff0000u);
      sacc[2] += w * __uint_as_float(v.y << 16);
      sacc[3] += w * __uint_as_float(v.y & 0xffff0000u);
      sacc[4] += w * __uint_as_float(v.z << 16);
      sacc[5] += w * __uint_as_float(v.z & 0xffff0000u);
      sacc[6] += w * __uint_as_float(v.w << 16);
      sacc[7] += w * __uint_as_float(v.w & 0xffff0000u);
    }
    u4 o;
    o.x = (unsigned)f2bf(sacc[0]) | ((unsigned)f2bf(sacc[1]) << 16);
    o.y = (unsigned)f2bf(sacc[2]) | ((unsigned)f2bf(sacc[3]) << 16);
    o.z = (unsigned)f2bf(sacc[4]) | ((unsigned)f2bf(sacc[5]) << 16);
    o.w = (unsigned)f2bf(sacc[6]) | ((unsigned)f2bf(sacc[7]) << 16);
    *(u4*)(kabar + (h * 1024 + b) * 512 + oct * 8) = o;
  } else {
    // TN 128x64: C[h][m0+..][256+n0+..] = sum_k attn2[h][k][m] * addk[k][n]
    int e = blockIdx.x;                        // 256 blocks: (8h, 8my, 4nx)
    int h = e >> 5, rem = e & 31, my = rem >> 2, nx = rem & 3;
    const ushort_t* A = attn2 + h * 262144;    // [k*1024 + m]
    const ushort_t* B = addk;                  // [k*256 + n]
    ushort_t* C = kabar + h * 524288;
    int m0 = my * 128, n0 = nx * 64;
    int t = threadIdx.x;
    int lane = t & 63, w = t >> 6;
    int quad = lane >> 4, l15 = lane & 15;
    int wm = w >> 1, wn = w & 1;
    f4 acc[4][2];
    #pragma unroll
    for (int mi = 0; mi < 4; ++mi)
      #pragma unroll
      for (int ni = 0; ni < 2; ++ni) acc[mi][ni] = (f4)0.f;
    int colA = t & 127, halfA = t >> 7;        // A: 128 rows, kpp halfA*4+i
    int colB = t & 63,  grpB  = t >> 6;        // B: 64 rows,  kpp grpB*2+i
    for (int k0 = 0; k0 < 256; k0 += 32) {
      if (k0) __syncthreads();
      #pragma unroll
      for (int i = 0; i < 4; ++i) {
        int kpp = halfA * 4 + i, kk = k0 + kpp * 4;
        unsigned x0 = A[(kk + 0) * 1024 + m0 + colA], x1 = A[(kk + 1) * 1024 + m0 + colA];
        unsigned x2 = A[(kk + 2) * 1024 + m0 + colA], x3 = A[(kk + 3) * 1024 + m0 + colA];
        uint2 va; va.x = x0 | (x1 << 16); va.y = x2 | (x3 << 16);
        *(uint2*)&Asu[colA * 20 + kpp * 2] = va;
      }
      #pragma unroll
      for (int i = 0; i < 2; ++i) {
        int kpp = grpB * 2 + i, kk = k0 + kpp * 4;
        unsigned y0 = B[(kk + 0) * 256 + n0 + colB], y1 = B[(kk + 1) * 256 + n0 + colB];
        unsigned y2 = B[(kk + 2) * 256 + n0 + colB], y3 = B[(kk + 3) * 256 + n0 + colB];
        uint2 vb; vb.x = y0 | (y1 << 16); vb.y = y2 | (y3 << 16);
        *(uint2*)&Bsu[colB * 20 + kpp * 2] = vb;
      }
      __syncthreads();
      bh8 af[4], bf2[2];
      #pragma unroll
      for (int mi = 0; mi < 4; ++mi)
        af[mi] = *(bh8*)((const ushort_t*)Asu + (wm * 64 + mi * 16 + l15) * 40 + quad * 8);
      #pragma unroll
      for (int ni = 0; ni < 2; ++ni)
        bf2[ni] = *(bh8*)((const ushort_t*)Bsu + (wn * 32 + ni * 16 + l15) * 40 + quad * 8);
      #pragma unroll
      for (int mi = 0; mi < 4; ++mi)
        #pragma unroll
        for (int ni = 0; ni < 2; ++ni)
          acc[mi][ni] = __builtin_amdgcn_mfma_f32_16x16x32_bf16(af[mi], bf2[ni], acc[mi][ni], 0, 0, 0);
    }
    #pragma unroll
    for (int mi = 0; mi < 4; ++mi)
      #pragma unroll
      for (int ni = 0; ni < 2; ++ni)
        #pragma unroll
        for (int r = 0; r < 4; ++r) {
          int mg = m0 + wm * 64 + mi * 16 + quad * 4 + r;
          int ng = n0 + wn * 32 + ni * 16 + l15;
          C[mg * 512 + 256 + ng] = f2bf(acc[mi][ni][r]);
        }
  }
}

// ---------------------------------------------------------------------------
// gemm_val (R9 form, frozen): 128x64 tiles -> 256 blocks.
// ---------------------------------------------------------------------------
__global__ __launch_bounds__(256) void gemm_val_k(
    const ushort_t* __restrict__ kabar, const ushort_t* __restrict__ Wcat,
    float* __restrict__ Y)
{
  __shared__ __align__(16) char smem[20480];
  int h = blockIdx.z;
  gemm_abt_12864(smem, kabar + h * 524288, Wcat + h * 131072, Y + h * 262144,
                 512, 512, 256, 512, blockIdx.y * 128, blockIdx.x * 64);
}

// ------------------------------- final combine ------------------------------
__global__ __launch_bounds__(256) void k_combine(
    const float* __restrict__ q, const float* __restrict__ Wmix,
    const float* __restrict__ Y,
    const float* __restrict__ s1, const float* __restrict__ s2,
    const float* __restrict__ bval, float* __restrict__ out)
{
  int b = blockIdx.x, c = threadIdx.x;
  float w[9];
  float m = -1e30f;
  #pragma unroll
  for (int j = 0; j < 9; ++j) { w[j] = Wmix[c * 9 + j]; m = fmaxf(m, w[j]); }
  float tot = 0.f;
  #pragma unroll
  for (int j = 0; j < 9; ++j) { w[j] = expf(w[j] - m); tot += w[j]; }
  float inv = 1.f / tot;
  float res = q[b * 256 + c] * w[8] * inv;
  #pragma unroll
  for (int hh = 0; hh < 8; ++hh) {
    float y = Y[(hh * 1024 + b) * 256 + c]
            + s1[hh * 1024 + b] * bval[(2 * hh) * 256 + c]
            + s2[hh * 1024 + b] * bval[(2 * hh + 1) * 256 + c];
    res += w[hh] * inv * y;
  }
  out[b * 256 + c] = res;
}

extern "C" void kernel_launch(void* const* d_in, const int* in_sizes, int n_in,
                              void* d_out, int out_size, void* d_ws, size_t ws_size,
                              hipStream_t stream) {
  (void)in_sizes; (void)n_in; (void)out_size; (void)ws_size;
  const float* q      = (const float*)d_in[0];
  const float* refpts = (const float*)d_in[1];
  const float* xin    = (const float*)d_in[2];
  const int*   shapes = (const int*)d_in[3];
  const float* addk   = (const float*)d_in[4];
  const int*   lvlst  = (const int*)d_in[5];
  const float* Woff   = (const float*)d_in[6];
  const float* boff   = (const float*)d_in[7];
  const float* Wattn  = (const float*)d_in[8];
  const float* Wval   = (const float*)d_in[9];
  const float* bval   = (const float*)d_in[10];
  const float* Wmix   = (const float*)d_in[11];
  float* out = (float*)d_out;
  float* ws  = (float*)d_ws;

  int*   fidx    = (int*)ws;                  // [0, 131072)
  float* s1      = ws + 393216;               // 8192
  float* s2      = ws + 401408;               // 8192
  float* attn    = ws + 409600;               // 8*272*1024 fp32 (dead after fused_d)
  float* Y       = ws + 409600;               // overlays attn (written by gemm_val_k)
  ushort_t* arena = (ushort_t*)(ws + 2637824);
  ushort_t* q_bf     = arena;                 // 262144
  ushort_t* xin_bf   = arena + 262144;        // 3403264
  ushort_t* addk_bf  = arena + 3665408;       // 65536
  ushort_t* Wcat_bf  = arena + 3730944;       // 1048576 (stride 131072/head)
  ushort_t* Wlvl_bf  = arena + 6352384;       // 2097152
  ushort_t* tmp_bf   = arena + 8449536;       // 524288
  ushort_t* attn2_bf = arena + 8973824;       // 2097152
  ushort_t* kabar_bf = arena + 11070976;      // 4194304 (8*1024*512)
  float* attnP = (float*)(arena + 15265280);  // 4 * 131072 f (per-ch partials)

  k_fused_cast_off<<<2048, 256, 0, stream>>>(q, xin, addk, Wval, Wattn, arena,
                                             Woff, boff, refpts, shapes, lvlst,
                                             fidx, tmp_bf);
  k_fused_attn<<<2304, 256, 0, stream>>>(q_bf, xin_bf, Wlvl_bf, fidx, attnP,
                                         tmp_bf, attn);
  k_softmax<<<dim3(64, 8), 512, 0, stream>>>(attn, attnP, attn2_bf, s1, s2);
  k_fused_kbar_tn<<<1280, 256, 0, stream>>>(xin_bf, attn, fidx, attn2_bf,
                                            addk_bf, kabar_bf);
  gemm_val_k<<<dim3(4, 8, 8), 256, 0, stream>>>(kabar_bf, Wcat_bf, Y);
  k_combine<<<1024, 256, 0, stream>>>(q, Wmix, Y, s1, s2, bval, out);
}